// Round 5
// baseline (268.917 us; speedup 1.0000x reference)
//
#include <hip/hip_runtime.h>
#include <stdint.h>

#define FEAT 128
#define ECH 2048   // edges per econv block
#define CAP 200000 // per-partition edge capacity
#define SCB 512    // scatter blocks in fused k_sg

typedef short bf16x8 __attribute__((ext_vector_type(8)));
typedef float f32x4 __attribute__((ext_vector_type(4)));
typedef float f32x2 __attribute__((ext_vector_type(2)));

__device__ __forceinline__ float bfs(unsigned short u) {
    uint32_t t = ((uint32_t)u) << 16;
    return __builtin_bit_cast(float, t);
}
__device__ __forceinline__ unsigned short f2bf(float f) {
    uint32_t u = __builtin_bit_cast(uint32_t, f);
    u += 0x7fffu + ((u >> 16) & 1u);
    return (unsigned short)(u >> 16);
}

// ---- fused prep: econv blocks [0,NE) | W blocks [NE,NE+64) | bias [+18) -
__launch_bounds__(256)
__global__ void k_prep(const int* __restrict__ ei,
                       int* __restrict__ dstb, int* __restrict__ srcb,
                       int* __restrict__ bcnt, int* __restrict__ deg,
                       int E, int n, int psz, int NE,
                       const void* W1, const void* W2,
                       const void* b1, const void* b2,
                       const void* Wfc, const void* bfc,
                       unsigned short* Wth1, unsigned short* Wth2,
                       float* b1f, float* b2f, float* Wfcf, float* bfcf) {
    int t = threadIdx.x;

    if ((int)blockIdx.x >= NE) {
        __shared__ int hits;
        int blk = blockIdx.x - NE;
        const void* sampsrc = (blk < 32) ? W1 : (blk < 64 ? W2 : Wfc);
        const uint32_t* samp = (const uint32_t*)sampsrc;
        if (t == 0) hits = 0;
        __syncthreads();
        unsigned ew = (samp[t] >> 7) & 0xFFu;
        unsigned long long bl = __ballot(ew >= 0x60u && ew <= 0x90u);
        if ((t & 63) == 0) atomicAdd(&hits, (int)__popcll(bl));
        __syncthreads();
        int isbf = (2 * hits > 256);

        if (blk < 64) {
            const void* W = (blk < 32) ? W1 : W2;
            unsigned short* th = (blk < 32) ? Wth1 : Wth2;
            int base = (blk & 31) * 512;
            #pragma unroll
            for (int j = 0; j < 2; j++) {
                int idx = base + t * 2 + j;
                int nn = idx >> 7, k = idx & 127;
                int si = k * 128 + nn;
                float f = isbf ? bfs(((const unsigned short*)W)[si])
                               : ((const float*)W)[si];
                th[nn * 128 + k] = f2bf(f);
            }
        } else {
            int i = (blk - 64) * 256 + t;
            if (i >= 4384) return;
            const void* src; float* dst; int off;
            if (i < 128)       { src = b1;  dst = b1f;  off = i; }
            else if (i < 256)  { src = b2;  dst = b2f;  off = i - 128; }
            else if (i < 4352) { src = Wfc; dst = Wfcf; off = i - 256; }
            else               { src = bfc; dst = bfcf; off = i - 4352; }
            dst[off] = isbf ? bfs(((const unsigned short*)src)[off])
                            : ((const float*)src)[off];
        }
        return;
    }

    // ---- econv part (+ zero its deg slice) ----
    __shared__ int lflag;
    __shared__ int cnt[8], lofs[8], gbase[8];
    __shared__ int stage_s[ECH];
    __shared__ int stage_d[ECH];
    __shared__ char sb[ECH];
    if (t < 128) {
        int di = blockIdx.x * 128 + t;
        if (di < n) deg[di] = 0;
    }
    if (t == 0) lflag = 0;
    if (t < 8) cnt[t] = 0;
    __syncthreads();
    if (ei[1 + 2 * t] != 0) atomicOr(&lflag, 1);   // odd words: 0 => int64
    __syncthreads();
    int is32 = lflag;

    int base = blockIdx.x * ECH;
    int s[8], d[8], p[8], slot[8];
    #pragma unroll
    for (int j = 0; j < 8; j++) {
        int e = base + j * 256 + t;
        int ss = 0, dd = 0;
        if (e < E) {
            ss = is32 ? ei[e]     : ei[2 * e];
            dd = is32 ? ei[E + e] : ei[2 * E + 2 * e];
            if ((unsigned)ss >= (unsigned)n) ss = 0;
            if ((unsigned)dd >= (unsigned)n) dd = 0;
            int pp = dd / psz;
            if (pp > 7) pp = 7;
            p[j] = pp;
            slot[j] = atomicAdd(&cnt[pp], 1);
        } else p[j] = -1;
        s[j] = ss; d[j] = dd;
    }
    __syncthreads();
    if (t == 0) {
        int acc = 0;
        #pragma unroll
        for (int i = 0; i < 8; i++) { lofs[i] = acc; acc += cnt[i]; }
    }
    __syncthreads();
    if (t < 8) gbase[t] = atomicAdd(&bcnt[t], cnt[t]);
    __syncthreads();
    #pragma unroll
    for (int j = 0; j < 8; j++) {
        if (p[j] >= 0) {
            int pos = lofs[p[j]] + slot[j];
            stage_s[pos] = s[j];
            stage_d[pos] = d[j];
            sb[pos] = (char)p[j];
        }
    }
    __syncthreads();
    int tot = lofs[7] + cnt[7];
    for (int i = t; i < tot; i += 256) {
        int pp = sb[i];
        int off = gbase[pp] + (i - lofs[pp]);
        if (off < CAP) {
            dstb[pp * CAP + off] = stage_d[i];
            srcb[pp * CAP + off] = stage_s[i];
        }
    }
}

// ---- partitioned degree count (dst-only read) ---------------------------
__launch_bounds__(256)
__global__ void k_degp(const int* __restrict__ dstb, const int* __restrict__ bcnt,
                       int* __restrict__ deg) {
    int p = blockIdx.x & 7;
    int nb = gridDim.x >> 3;
    int cnt = bcnt[p]; if (cnt > CAP) cnt = CAP;
    const int* db = dstb + p * CAP;
    for (int i = (blockIdx.x >> 3) * 256 + threadIdx.x; i < cnt; i += nb * 256)
        atomicAdd(&deg[db[i]], 1);
}

// ---- block sums (+ fused dinv) ------------------------------------------
__global__ void k_bsum(const int* __restrict__ deg, int* __restrict__ bsum,
                       float* __restrict__ dinv, int n) {
    __shared__ int ws[4];
    int t = threadIdx.x, lane = t & 63, w = t >> 6;
    int idx = blockIdx.x * 256 + t;
    int v = (idx < n) ? deg[idx] : 0;
    if (idx < n) dinv[idx] = rsqrtf((float)(v + 1));  // +1 self-loop
    int r = v;
    #pragma unroll
    for (int off = 32; off > 0; off >>= 1) r += __shfl_down(r, off, 64);
    if (lane == 0) ws[w] = r;
    __syncthreads();
    if (t == 0) bsum[blockIdx.x] = ws[0] + ws[1] + ws[2] + ws[3];
}

// ---- apply with self-computed block offset ------------------------------
__launch_bounds__(256)
__global__ void k_bapply2(const int* __restrict__ deg, const int* __restrict__ bsum,
                          int* __restrict__ row_ptr, int* __restrict__ cursor,
                          int n, int nb) {
    __shared__ int wred[4];
    __shared__ int wsum[4];
    __shared__ int boffs;
    int b = blockIdx.x, t = threadIdx.x, lane = t & 63, w = t >> 6;

    int pv = (t < b && t < nb) ? bsum[t] : 0;
    #pragma unroll
    for (int off = 32; off > 0; off >>= 1) pv += __shfl_down(pv, off, 64);
    if (lane == 0) wred[w] = pv;
    __syncthreads();
    if (t == 0) boffs = wred[0] + wred[1] + wred[2] + wred[3];
    __syncthreads();

    int idx = b * 256 + t;
    int v = (idx < n) ? deg[idx] : 0;
    int s = v;
    #pragma unroll
    for (int off = 1; off < 64; off <<= 1) {
        int x = __shfl_up(s, off, 64);
        if (lane >= off) s += x;
    }
    if (lane == 63) wsum[w] = s;
    __syncthreads();
    if (t == 0) {
        int acc = 0;
        #pragma unroll
        for (int i = 0; i < 4; i++) { int x = wsum[i]; wsum[i] = acc; acc += x; }
    }
    __syncthreads();
    int ex = boffs + s - v + wsum[w];
    if (idx < n) {
        row_ptr[idx] = ex;
        cursor[idx]  = ex;
    }
    if (idx == n - 1) row_ptr[n] = ex + v;
}

// ---- GEMM tile body: hs8 = fp8(dinv[row]*(X @ W)) -----------------------
__device__ __forceinline__ void gemm_body(const void* __restrict__ X,
                                          const unsigned short* __restrict__ Wth,
                                          const float* __restrict__ dinv,
                                          uint32_t* __restrict__ hs8,
                                          int n, int tile, int l,
                                          unsigned char* __restrict__ ldsrow) {
    int quad = l >> 4;
    int m16 = l & 15;
    int r0 = tile * 16;

    unsigned ew = (((const uint32_t*)X)[l] >> 7) & 0xFFu;
    unsigned long long bl = __ballot(ew >= 0x60u && ew <= 0x90u);
    int isbf = ((int)__popcll(bl) * 2 > 64) ? 1 : 0;

    int ra = r0 + m16;
    if (ra > n - 1) ra = n - 1;
    bf16x8 ah[4];
    if (isbf) {
        const int4* Xv = (const int4*)X;
        #pragma unroll
        for (int kt = 0; kt < 4; kt++)
            ah[kt] = __builtin_bit_cast(bf16x8, Xv[ra * 16 + kt * 4 + quad]);
    } else {
        const float4* Xf = (const float4*)X;
        #pragma unroll
        for (int kt = 0; kt < 4; kt++) {
            int jj = kt * 4 + quad;
            float4 fa = Xf[ra * 32 + jj * 2];
            float4 fb = Xf[ra * 32 + jj * 2 + 1];
            float v[8] = {fa.x, fa.y, fa.z, fa.w, fb.x, fb.y, fb.z, fb.w};
            bf16x8 h;
            #pragma unroll
            for (int j = 0; j < 8; j++) h[j] = (short)f2bf(v[j]);
            ah[kt] = h;
        }
    }

    float dv[4];
    #pragma unroll
    for (int reg = 0; reg < 4; reg++) {
        int row = r0 + quad * 4 + reg;
        if (row > n - 1) row = n - 1;
        dv[reg] = dinv[row];
    }

    const int4* Wvh = (const int4*)Wth;
    #pragma unroll
    for (int nt = 0; nt < 8; nt++) {
        f32x4 acc = {0.f, 0.f, 0.f, 0.f};
        int brow = (nt * 16 + m16) * 16;
        #pragma unroll
        for (int kt = 0; kt < 4; kt++) {
            bf16x8 bh = __builtin_bit_cast(bf16x8, Wvh[brow + kt * 4 + quad]);
            acc = __builtin_amdgcn_mfma_f32_16x16x32_bf16(ah[kt], bh, acc, 0, 0, 0);
        }
        #pragma unroll
        for (int reg = 0; reg < 4; reg++) {
            float v = acc[reg] * dv[reg];
            int pk = __builtin_amdgcn_cvt_pk_fp8_f32(v, v, 0, false);
            ldsrow[(quad * 4 + reg) * 128 + nt * 16 + m16] = (unsigned char)(pk & 0xFF);
        }
    }
    __syncthreads();
    const uint32_t* l32 = (const uint32_t*)ldsrow;
    #pragma unroll
    for (int i = 0; i < 8; i++) {
        int idx = i * 64 + l;
        int row = idx >> 5;
        int grow = r0 + row;
        if (grow < n) hs8[grow * 32 + (idx & 31)] = l32[idx];
    }
}

// ---- fused: scatter [0,SCB) || GEMM layer-1 [SCB,..) --------------------
__launch_bounds__(256)
__global__ void k_sg(const int* __restrict__ dstb, const int* __restrict__ srcb,
                     const int* __restrict__ bcnt,
                     int* __restrict__ cursor, int* __restrict__ col, int E,
                     const void* __restrict__ X,
                     const unsigned short* __restrict__ Wth,
                     const float* __restrict__ dinv,
                     uint32_t* __restrict__ hs8, int n) {
    __shared__ unsigned char lds8[4][16 * 128];
    int b = blockIdx.x;
    if (b < SCB) {
        int p = b & 7;
        int nb = SCB >> 3;
        int cnt = bcnt[p]; if (cnt > CAP) cnt = CAP;
        const int* db = dstb + p * CAP;
        const int* sb = srcb + p * CAP;
        for (int i = (b >> 3) * 256 + threadIdx.x; i < cnt; i += nb * 256) {
            int pos = atomicAdd(&cursor[db[i]], 1);
            if ((unsigned)pos < (unsigned)E) col[pos] = sb[i];
        }
        return;
    }
    int wave = threadIdx.x >> 6;
    int l = threadIdx.x & 63;
    gemm_body(X, Wth, dinv, hs8, n, (b - SCB) * 4 + wave, l, lds8[wave]);
}

// ---- fused agg-1 + GEMM-2: block owns 16 nodes, 16 waves ----------------
// Phase A: ONE NODE PER WAVE (r4 post-mortem: k_agg's 1-node/wave layout is
//   measurably faster than 4-sequential-nodes at identical gather volume --
//   4x TLP, 1/4 the per-wave dependent chain). Paired-row dword gather
//   (lanes 0-31 = edge 2j, 32-63 = edge 2j+1) + single masked tail round.
// Phase B: waves 0-7 each compute one nt-slice of the 16-row MFMA tile.
__launch_bounds__(1024)
__global__ void k_agg1gemm2(const unsigned short* __restrict__ hsv,
                            const int* __restrict__ row_ptr,
                            const int* __restrict__ col,
                            const float* __restrict__ dinv,
                            const float* __restrict__ bias,
                            const unsigned short* __restrict__ Wth2,
                            uint32_t* __restrict__ hs8out, int n, int E) {
    __shared__ __align__(16) unsigned short actlds[16 * 136]; // stride 136: bank-safe
    __shared__ unsigned char pack[16 * 128];
    int wave = threadIdx.x >> 6;          // 0..15 = node slot
    int lane = threadIdx.x & 63;
    int lane32 = lane & 31;
    int half = lane >> 5;
    int tile0 = blockIdx.x * 16;
    const uint32_t* hsw = (const uint32_t*)hsv;   // row = 32 dwords (128 fp8)
    float4 bu = ((const float4*)bias)[lane32];

    // ---- Phase A: one node per wave ----
    int node = tile0 + wave;
    bool active = (node < n);
    int nd = active ? node : 0;

    uint32_t selfw = hsw[nd * 32 + lane32];
    int e = row_ptr[nd];
    int end = active ? row_ptr[nd + 1] : e;
    if (e < 0) e = 0;
    if (end > E) end = E;
    if (end < e) end = e;

    f32x2 slo = __builtin_amdgcn_cvt_pk_f32_fp8((int)selfw, false);
    f32x2 shi = __builtin_amdgcn_cvt_pk_f32_fp8((int)selfw, true);
    float a0, a1, a2, a3;
    if (half == 0) { a0 = slo.x; a1 = slo.y; a2 = shi.x; a3 = shi.y; }
    else           { a0 = 0.f;  a1 = 0.f;  a2 = 0.f;  a3 = 0.f;  }

    for (; e + 16 <= end; e += 16) {
        uint32_t uu[8];
        #pragma unroll
        for (int j = 0; j < 8; j++) {
            unsigned s = (unsigned)col[e + 2 * j + half];
            if (s >= (unsigned)n) s = 0;
            uu[j] = hsw[s * 32 + lane32];
        }
        #pragma unroll
        for (int j = 0; j < 8; j++) {
            f32x2 lo = __builtin_amdgcn_cvt_pk_f32_fp8((int)uu[j], false);
            f32x2 hi = __builtin_amdgcn_cvt_pk_f32_fp8((int)uu[j], true);
            a0 += lo.x; a1 += lo.y; a2 += hi.x; a3 += hi.y;
        }
    }
    if (e < end) {                      // ONE masked round covers the tail
        uint32_t uu[8];
        #pragma unroll
        for (int j = 0; j < 8; j++) {
            int ej = e + 2 * j + half;
            int ec = (ej < end) ? ej : (end - 1);
            unsigned s = (unsigned)col[ec];
            if (s >= (unsigned)n) s = 0;
            uu[j] = hsw[s * 32 + lane32];
        }
        #pragma unroll
        for (int j = 0; j < 8; j++) {
            float m = ((e + 2 * j + half) < end) ? 1.0f : 0.0f;
            f32x2 lo = __builtin_amdgcn_cvt_pk_f32_fp8((int)uu[j], false);
            f32x2 hi = __builtin_amdgcn_cvt_pk_f32_fp8((int)uu[j], true);
            a0 = fmaf(m, lo.x, a0); a1 = fmaf(m, lo.y, a1);
            a2 = fmaf(m, hi.x, a2); a3 = fmaf(m, hi.y, a3);
        }
    }
    // combine lane halves
    a0 += __shfl_xor(a0, 32, 64);
    a1 += __shfl_xor(a1, 32, 64);
    a2 += __shfl_xor(a2, 32, 64);
    a3 += __shfl_xor(a3, 32, 64);

    float dv = dinv[nd];
    float r0 = fmaxf(dv * a0 + bu.x, 0.f);
    float r1 = fmaxf(dv * a1 + bu.y, 0.f);
    float r2 = fmaxf(dv * a2 + bu.z, 0.f);
    float r3 = fmaxf(dv * a3 + bu.w, 0.f);
    if (!active) { r0 = 0.f; r1 = 0.f; r2 = 0.f; r3 = 0.f; }
    if (half == 0) {
        uint32_t w0 = (uint32_t)f2bf(r0) | ((uint32_t)f2bf(r1) << 16);
        uint32_t w1 = (uint32_t)f2bf(r2) | ((uint32_t)f2bf(r3) << 16);
        *(uint2*)&actlds[wave * 136 + 4 * lane32] = make_uint2(w0, w1);
    }
    __syncthreads();

    // ---- Phase B: waves 0-7, one nt-slice each (A from actlds) ----
    if (wave < 8) {
        int quad = lane >> 4;
        int m16 = lane & 15;
        bf16x8 ah[4];
        #pragma unroll
        for (int kt = 0; kt < 4; kt++) {
            const unsigned short* p = &actlds[m16 * 136 + kt * 32 + quad * 8];
            ah[kt] = __builtin_bit_cast(bf16x8, *(const int4*)p);
        }
        float dv4[4];
        #pragma unroll
        for (int reg = 0; reg < 4; reg++) {
            int row = tile0 + quad * 4 + reg;
            if (row > n - 1) row = n - 1;
            dv4[reg] = dinv[row];
        }
        const int4* Wvh = (const int4*)Wth2;
        int nt = wave;
        f32x4 acc = {0.f, 0.f, 0.f, 0.f};
        int brow = (nt * 16 + m16) * 16;
        #pragma unroll
        for (int kt = 0; kt < 4; kt++) {
            bf16x8 bh = __builtin_bit_cast(bf16x8, Wvh[brow + kt * 4 + quad]);
            acc = __builtin_amdgcn_mfma_f32_16x16x32_bf16(ah[kt], bh, acc, 0, 0, 0);
        }
        #pragma unroll
        for (int reg = 0; reg < 4; reg++) {
            float v = acc[reg] * dv4[reg];
            int pk = __builtin_amdgcn_cvt_pk_fp8_f32(v, v, 0, false);
            pack[(quad * 4 + reg) * 128 + nt * 16 + m16] = (unsigned char)(pk & 0xFF);
        }
    }
    __syncthreads();
    if (threadIdx.x < 512) {
        const uint32_t* l32 = (const uint32_t*)pack;
        int idx = threadIdx.x;             // 0..511
        int row = idx >> 5;
        int grow = tile0 + row;
        if (grow < n) hs8out[grow * 32 + (idx & 31)] = l32[idx];
    }
}

// ---- Pull aggregation layer-2 (fp8 hs, pre-scaled) -> pooled partials ---
// Paired-row dword gather + single masked tail round (same as agg1gemm2).
__launch_bounds__(256)
__global__ void k_agg(const unsigned short* __restrict__ hsv,
                      const int* __restrict__ row_ptr,
                      const int* __restrict__ col, const float* __restrict__ dinv,
                      const float* __restrict__ bias,
                      float* __restrict__ partial, int n, int E) {
    __shared__ __align__(16) float pl[4][128];
    int wave = threadIdx.x >> 6;
    int lane = threadIdx.x & 63;
    int lane32 = lane & 31;
    int half = lane >> 5;
    int node = blockIdx.x * 4 + wave;
    bool active = (node < n);
    int nd = active ? node : 0;
    const uint32_t* hsw = (const uint32_t*)hsv;

    uint32_t selfw = hsw[nd * 32 + lane32];
    int e = row_ptr[nd];
    int end = active ? row_ptr[nd + 1] : e;
    if (e < 0) e = 0;
    if (end > E) end = E;
    if (end < e) end = e;

    f32x2 slo = __builtin_amdgcn_cvt_pk_f32_fp8((int)selfw, false);
    f32x2 shi = __builtin_amdgcn_cvt_pk_f32_fp8((int)selfw, true);
    float a0, a1, a2, a3;
    if (half == 0) { a0 = slo.x; a1 = slo.y; a2 = shi.x; a3 = shi.y; }
    else           { a0 = 0.f;  a1 = 0.f;  a2 = 0.f;  a3 = 0.f;  }

    for (; e + 16 <= end; e += 16) {
        uint32_t uu[8];
        #pragma unroll
        for (int j = 0; j < 8; j++) {
            unsigned s = (unsigned)col[e + 2 * j + half];
            if (s >= (unsigned)n) s = 0;
            uu[j] = hsw[s * 32 + lane32];
        }
        #pragma unroll
        for (int j = 0; j < 8; j++) {
            f32x2 lo = __builtin_amdgcn_cvt_pk_f32_fp8((int)uu[j], false);
            f32x2 hi = __builtin_amdgcn_cvt_pk_f32_fp8((int)uu[j], true);
            a0 += lo.x; a1 += lo.y; a2 += hi.x; a3 += hi.y;
        }
    }
    if (e < end) {                          // ONE masked round covers the tail
        uint32_t uu[8];
        #pragma unroll
        for (int j = 0; j < 8; j++) {
            int ej = e + 2 * j + half;
            int ec = (ej < end) ? ej : (end - 1);
            unsigned s = (unsigned)col[ec];
            if (s >= (unsigned)n) s = 0;
            uu[j] = hsw[s * 32 + lane32];
        }
        #pragma unroll
        for (int j = 0; j < 8; j++) {
            float m = ((e + 2 * j + half) < end) ? 1.0f : 0.0f;
            f32x2 lo = __builtin_amdgcn_cvt_pk_f32_fp8((int)uu[j], false);
            f32x2 hi = __builtin_amdgcn_cvt_pk_f32_fp8((int)uu[j], true);
            a0 = fmaf(m, lo.x, a0); a1 = fmaf(m, lo.y, a1);
            a2 = fmaf(m, hi.x, a2); a3 = fmaf(m, hi.y, a3);
        }
    }
    a0 += __shfl_xor(a0, 32, 64);
    a1 += __shfl_xor(a1, 32, 64);
    a2 += __shfl_xor(a2, 32, 64);
    a3 += __shfl_xor(a3, 32, 64);

    float dv = dinv[nd];
    float4 bu = ((const float4*)bias)[lane32];
    float r0 = fmaxf(dv * a0 + bu.x, 0.f);
    float r1 = fmaxf(dv * a1 + bu.y, 0.f);
    float r2 = fmaxf(dv * a2 + bu.z, 0.f);
    float r3 = fmaxf(dv * a3 + bu.w, 0.f);
    if (!active) { r0 = 0.f; r1 = 0.f; r2 = 0.f; r3 = 0.f; }

    if (half == 0)
        *(float4*)&pl[wave][4 * lane32] = make_float4(r0, r1, r2, r3);
    __syncthreads();
    int t = threadIdx.x;
    if (t < 128) {
        float ps = pl[0][t] + pl[1][t] + pl[2][t] + pl[3][t];
        partial[blockIdx.x * 128 + t] = ps;
    }
}

// ---- fused pooled reduce + FC (last-block pattern) ----------------------
__launch_bounds__(256)
__global__ void k_redfinal(const float* __restrict__ partial, float* __restrict__ pooled,
                           int* __restrict__ done,
                           const float* __restrict__ Wfcf, const float* __restrict__ bfcf,
                           const void* __restrict__ x, void* __restrict__ out,
                           int n, int nbrows, int gblocks) {
    __shared__ float red[8][128];
    int t = threadIdx.x;
    int chunk = (nbrows + gblocks - 1) / gblocks;
    int r0 = blockIdx.x * chunk;
    int r1 = r0 + chunk;
    if (r1 > nbrows) r1 = nbrows;

    float4 acc = {0.f, 0.f, 0.f, 0.f};
    const float4* p4 = (const float4*)partial;
    for (int i = r0 * 32 + t; i < r1 * 32; i += 256) {
        float4 v = p4[i];
        acc.x += v.x; acc.y += v.y; acc.z += v.z; acc.w += v.w;
    }
    int g = t >> 5;
    int fb = (t & 31) * 4;
    red[g][fb]     = acc.x;
    red[g][fb + 1] = acc.y;
    red[g][fb + 2] = acc.z;
    red[g][fb + 3] = acc.w;
    __syncthreads();
    if (t < 128) {
        float s = red[0][t] + red[1][t] + red[2][t] + red[3][t]
                + red[4][t] + red[5][t] + red[6][t] + red[7][t];
        atomicAdd(&pooled[t], s);
    }
    __threadfence();
    __shared__ int lastf;
    if (t == 0) lastf = (atomicAdd(done, 1) == gblocks - 1) ? 1 : 0;
    __syncthreads();
    if (!lastf) return;

    __shared__ int hits;
    __shared__ float pv[128];
    if (t == 0) hits = 0;
    __syncthreads();
    unsigned ew = (((const uint32_t*)x)[t] >> 7) & 0xFFu;
    unsigned long long bl = __ballot(ew >= 0x60u && ew <= 0x90u);
    if ((t & 63) == 0) atomicAdd(&hits, (int)__popcll(bl));
    if (t < 128)
        pv[t] = __hip_atomic_load(&pooled[t], __ATOMIC_RELAXED,
                                  __HIP_MEMORY_SCOPE_AGENT);
    __syncthreads();
    int isbf = (2 * hits > 256);
    if (t < 32) {
        float s = 0.f;
        for (int c = 0; c < 128; ++c) s += pv[c] * Wfcf[c * 32 + t];
        s = s * (1.0f / (float)n) + bfcf[t];
        if (isbf) ((unsigned short*)out)[t] = f2bf(s);
        else      ((float*)out)[t] = s;
    }
}

// ---- Launch -------------------------------------------------------------

extern "C" void kernel_launch(void* const* d_in, const int* in_sizes, int n_in,
                              void* d_out, int out_size, void* d_ws, size_t ws_size,
                              hipStream_t stream) {
    const void* x   = d_in[0];
    const int*  ei  = (const int*)d_in[1];
    const void* W1  = d_in[2];
    const void* b1  = d_in[3];
    const void* W2  = d_in[4];
    const void* b2  = d_in[5];
    const void* Wfc = d_in[6];
    const void* bfc = d_in[7];

    const int n = in_sizes[0] / FEAT;    // 50000
    const int E = in_sizes[1] / 2;       // 800000
    const int nagg = (n + 3) / 4;        // 12500
    const int ntile = (n + 15) / 16;     // 3125
    const int psz  = (n + 7) / 8;        // 6250
    const int nscan = (n + 255) / 256;   // 196
    const int NE   = (E + ECH - 1) / ECH;// 391
    const int gemm_grid = (ntile + 3) / 4; // 782

    char* ws = (char*)d_ws;
    uint32_t*       hs8     = (uint32_t*)(ws);                     // 6.4MB used
    uint32_t*       hs8b    = (uint32_t*)(ws + 12800000);          // 6.4MB (layer-2 hs)
    float*          partial = (float*)(ws + 25600000);             // 6.4MB used
    int*            col     = (int*)(ws + 38400000);               // 3.2MB
    int*            dstb    = (int*)(ws + 41600000);               // 6.4MB (8*CAP)
    int*            srcb    = (int*)(ws + 48000000);               // 6.4MB
    int*            deg     = (int*)(ws + 54400000);               // 200,000
    int*            row_ptr = (int*)(ws + 54600000);               // 200,016
    int*            cursor  = (int*)(ws + 54800016);               // 200,000
    float*          dinv    = (float*)(ws + 55000016);             // 200,000
    unsigned short* Wth1    = (unsigned short*)(ws + 55200016);    // 32,768
    unsigned short* Wth2    = (unsigned short*)(ws + 55232784);    // 32,768
    float*          b1f     = (float*)(ws + 55265552);             // 512
    float*          b2f     = (float*)(ws + 55266064);             // 512
    float*          Wfcf    = (float*)(ws + 55266576);             // 16,384
    float*          bfcf    = (float*)(ws + 55282960);             // 128
    // zero region (one memset): pooled | bcnt | done(+pad) | bsum
    float*          pooled  = (float*)(ws + 55283088);             // 512
    int*            bcnt    = (int*)(ws + 55283600);               // 32
    int*            done    = (int*)(ws + 55283632);               // 4 (+12 pad)
    int*            bsum    = (int*)(ws + 55283648);               // 784

    if (ws_size < 55284448) return;  // diagnostic: zero output => ws too small

    hipMemsetAsync(pooled, 0, 1344, stream);

    // 1) fused prep: edge decode+bucket (+deg zero) | weight/bias prep
    k_prep<<<NE + 82, 256, 0, stream>>>(ei, dstb, srcb, bcnt, deg, E, n, psz, NE,
                                        W1, W2, b1, b2, Wfc, bfc,
                                        Wth1, Wth2, b1f, b2f, Wfcf, bfcf);
    // 2) CSR: degree -> scan (boundaries are the cheap sync -- R11)
    k_degp<<<512, 256, 0, stream>>>(dstb, bcnt, deg);
    k_bsum<<<nscan, 256, 0, stream>>>(deg, bsum, dinv, n);
    k_bapply2<<<nscan, 256, 0, stream>>>(deg, bsum, row_ptr, cursor, n, nscan);
    // 3) fused: scatter || GEMM layer-1 (both dep only on bapply)
    k_sg<<<SCB + gemm_grid, 256, 0, stream>>>(dstb, srcb, bcnt, cursor, col, E,
                                              x, Wth1, dinv, hs8, n);
    // 4) fused agg-1 + GEMM-2, 1024 threads: one node per wave (r4)
    k_agg1gemm2<<<ntile, 1024, 0, stream>>>((const unsigned short*)hs8, row_ptr,
                                            col, dinv, b1f, Wth2, hs8b, n, E);
    // 5) agg-2 -> pooled partials
    k_agg<<<nagg, 256, 0, stream>>>((const unsigned short*)hs8b, row_ptr, col,
                                    dinv, b2f, partial, n, E);
    // 6) fused pooled-reduce + FC
    k_redfinal<<<100, 256, 0, stream>>>(partial, pooled, done, Wfcf, bfcf,
                                        x, d_out, n, nagg, 100);
}

// Round 7
// 262.482 us; speedup vs baseline: 1.0245x; 1.0245x over previous
//
#include <hip/hip_runtime.h>
#include <stdint.h>

#define FEAT 128
#define ECH 2048   // edges per econv block
#define CAP 200000 // per-partition edge capacity
#define SCB 512    // scatter blocks in fused k_sg

typedef short bf16x8 __attribute__((ext_vector_type(8)));
typedef float f32x4 __attribute__((ext_vector_type(4)));
typedef float f32x2 __attribute__((ext_vector_type(2)));

__device__ __forceinline__ float bfs(unsigned short u) {
    uint32_t t = ((uint32_t)u) << 16;
    return __builtin_bit_cast(float, t);
}
__device__ __forceinline__ unsigned short f2bf(float f) {
    uint32_t u = __builtin_bit_cast(uint32_t, f);
    u += 0x7fffu + ((u >> 16) & 1u);
    return (unsigned short)(u >> 16);
}

// accumulate one int2 (8 fp8 features) into a[8] with mask m
__device__ __forceinline__ void acc8(int2 u, float m, float* a) {
    f32x2 t;
    t = __builtin_amdgcn_cvt_pk_f32_fp8(u.x, false);
    a[0] = fmaf(m, t.x, a[0]); a[1] = fmaf(m, t.y, a[1]);
    t = __builtin_amdgcn_cvt_pk_f32_fp8(u.x, true);
    a[2] = fmaf(m, t.x, a[2]); a[3] = fmaf(m, t.y, a[3]);
    t = __builtin_amdgcn_cvt_pk_f32_fp8(u.y, false);
    a[4] = fmaf(m, t.x, a[4]); a[5] = fmaf(m, t.y, a[5]);
    t = __builtin_amdgcn_cvt_pk_f32_fp8(u.y, true);
    a[6] = fmaf(m, t.x, a[6]); a[7] = fmaf(m, t.y, a[7]);
}

// ---- fused prep: econv blocks [0,NE) | W blocks [NE,NE+64) | bias [+18) -
__launch_bounds__(256)
__global__ void k_prep(const int* __restrict__ ei,
                       int* __restrict__ dstb, int* __restrict__ srcb,
                       int* __restrict__ bcnt, int* __restrict__ deg,
                       int E, int n, int psz, int NE,
                       const void* W1, const void* W2,
                       const void* b1, const void* b2,
                       const void* Wfc, const void* bfc,
                       unsigned short* Wth1, unsigned short* Wth2,
                       float* b1f, float* b2f, float* Wfcf, float* bfcf) {
    int t = threadIdx.x;

    if ((int)blockIdx.x >= NE) {
        __shared__ int hits;
        int blk = blockIdx.x - NE;
        const void* sampsrc = (blk < 32) ? W1 : (blk < 64 ? W2 : Wfc);
        const uint32_t* samp = (const uint32_t*)sampsrc;
        if (t == 0) hits = 0;
        __syncthreads();
        unsigned ew = (samp[t] >> 7) & 0xFFu;
        unsigned long long bl = __ballot(ew >= 0x60u && ew <= 0x90u);
        if ((t & 63) == 0) atomicAdd(&hits, (int)__popcll(bl));
        __syncthreads();
        int isbf = (2 * hits > 256);

        if (blk < 64) {
            const void* W = (blk < 32) ? W1 : W2;
            unsigned short* th = (blk < 32) ? Wth1 : Wth2;
            int base = (blk & 31) * 512;
            #pragma unroll
            for (int j = 0; j < 2; j++) {
                int idx = base + t * 2 + j;
                int nn = idx >> 7, k = idx & 127;
                int si = k * 128 + nn;
                float f = isbf ? bfs(((const unsigned short*)W)[si])
                               : ((const float*)W)[si];
                th[nn * 128 + k] = f2bf(f);
            }
        } else {
            int i = (blk - 64) * 256 + t;
            if (i >= 4384) return;
            const void* src; float* dst; int off;
            if (i < 128)       { src = b1;  dst = b1f;  off = i; }
            else if (i < 256)  { src = b2;  dst = b2f;  off = i - 128; }
            else if (i < 4352) { src = Wfc; dst = Wfcf; off = i - 256; }
            else               { src = bfc; dst = bfcf; off = i - 4352; }
            dst[off] = isbf ? bfs(((const unsigned short*)src)[off])
                            : ((const float*)src)[off];
        }
        return;
    }

    // ---- econv part (+ zero its deg slice) ----
    __shared__ int lflag;
    __shared__ int cnt[8], lofs[8], gbase[8];
    __shared__ int stage_s[ECH];
    __shared__ int stage_d[ECH];
    __shared__ char sb[ECH];
    if (t < 128) {
        int di = blockIdx.x * 128 + t;
        if (di < n) deg[di] = 0;
    }
    if (t == 0) lflag = 0;
    if (t < 8) cnt[t] = 0;
    __syncthreads();
    if (ei[1 + 2 * t] != 0) atomicOr(&lflag, 1);   // odd words: 0 => int64
    __syncthreads();
    int is32 = lflag;

    int base = blockIdx.x * ECH;
    int s[8], d[8], p[8], slot[8];
    #pragma unroll
    for (int j = 0; j < 8; j++) {
        int e = base + j * 256 + t;
        int ss = 0, dd = 0;
        if (e < E) {
            ss = is32 ? ei[e]     : ei[2 * e];
            dd = is32 ? ei[E + e] : ei[2 * E + 2 * e];
            if ((unsigned)ss >= (unsigned)n) ss = 0;
            if ((unsigned)dd >= (unsigned)n) dd = 0;
            int pp = dd / psz;
            if (pp > 7) pp = 7;
            p[j] = pp;
            slot[j] = atomicAdd(&cnt[pp], 1);
        } else p[j] = -1;
        s[j] = ss; d[j] = dd;
    }
    __syncthreads();
    if (t == 0) {
        int acc = 0;
        #pragma unroll
        for (int i = 0; i < 8; i++) { lofs[i] = acc; acc += cnt[i]; }
    }
    __syncthreads();
    if (t < 8) gbase[t] = atomicAdd(&bcnt[t], cnt[t]);
    __syncthreads();
    #pragma unroll
    for (int j = 0; j < 8; j++) {
        if (p[j] >= 0) {
            int pos = lofs[p[j]] + slot[j];
            stage_s[pos] = s[j];
            stage_d[pos] = d[j];
            sb[pos] = (char)p[j];
        }
    }
    __syncthreads();
    int tot = lofs[7] + cnt[7];
    for (int i = t; i < tot; i += 256) {
        int pp = sb[i];
        int off = gbase[pp] + (i - lofs[pp]);
        if (off < CAP) {
            dstb[pp * CAP + off] = stage_d[i];
            srcb[pp * CAP + off] = stage_s[i];
        }
    }
}

// ---- partitioned degree count (dst-only read) ---------------------------
__launch_bounds__(256)
__global__ void k_degp(const int* __restrict__ dstb, const int* __restrict__ bcnt,
                       int* __restrict__ deg) {
    int p = blockIdx.x & 7;
    int nb = gridDim.x >> 3;
    int cnt = bcnt[p]; if (cnt > CAP) cnt = CAP;
    const int* db = dstb + p * CAP;
    for (int i = (blockIdx.x >> 3) * 256 + threadIdx.x; i < cnt; i += nb * 256)
        atomicAdd(&deg[db[i]], 1);
}

// ---- block sums (+ fused dinv) ------------------------------------------
__global__ void k_bsum(const int* __restrict__ deg, int* __restrict__ bsum,
                       float* __restrict__ dinv, int n) {
    __shared__ int ws[4];
    int t = threadIdx.x, lane = t & 63, w = t >> 6;
    int idx = blockIdx.x * 256 + t;
    int v = (idx < n) ? deg[idx] : 0;
    if (idx < n) dinv[idx] = rsqrtf((float)(v + 1));  // +1 self-loop
    int r = v;
    #pragma unroll
    for (int off = 32; off > 0; off >>= 1) r += __shfl_down(r, off, 64);
    if (lane == 0) ws[w] = r;
    __syncthreads();
    if (t == 0) bsum[blockIdx.x] = ws[0] + ws[1] + ws[2] + ws[3];
}

// ---- apply with self-computed block offset ------------------------------
__launch_bounds__(256)
__global__ void k_bapply2(const int* __restrict__ deg, const int* __restrict__ bsum,
                          int* __restrict__ row_ptr, int* __restrict__ cursor,
                          int n, int nb) {
    __shared__ int wred[4];
    __shared__ int wsum[4];
    __shared__ int boffs;
    int b = blockIdx.x, t = threadIdx.x, lane = t & 63, w = t >> 6;

    int pv = (t < b && t < nb) ? bsum[t] : 0;
    #pragma unroll
    for (int off = 32; off > 0; off >>= 1) pv += __shfl_down(pv, off, 64);
    if (lane == 0) wred[w] = pv;
    __syncthreads();
    if (t == 0) boffs = wred[0] + wred[1] + wred[2] + wred[3];
    __syncthreads();

    int idx = b * 256 + t;
    int v = (idx < n) ? deg[idx] : 0;
    int s = v;
    #pragma unroll
    for (int off = 1; off < 64; off <<= 1) {
        int x = __shfl_up(s, off, 64);
        if (lane >= off) s += x;
    }
    if (lane == 63) wsum[w] = s;
    __syncthreads();
    if (t == 0) {
        int acc = 0;
        #pragma unroll
        for (int i = 0; i < 4; i++) { int x = wsum[i]; wsum[i] = acc; acc += x; }
    }
    __syncthreads();
    int ex = boffs + s - v + wsum[w];
    if (idx < n) {
        row_ptr[idx] = ex;
        cursor[idx]  = ex;
    }
    if (idx == n - 1) row_ptr[n] = ex + v;
}

// ---- GEMM tile body: hs8 = fp8(dinv[row]*(X @ W)) -----------------------
__device__ __forceinline__ void gemm_body(const void* __restrict__ X,
                                          const unsigned short* __restrict__ Wth,
                                          const float* __restrict__ dinv,
                                          uint32_t* __restrict__ hs8,
                                          int n, int tile, int l,
                                          unsigned char* __restrict__ ldsrow) {
    int quad = l >> 4;
    int m16 = l & 15;
    int r0 = tile * 16;

    unsigned ew = (((const uint32_t*)X)[l] >> 7) & 0xFFu;
    unsigned long long bl = __ballot(ew >= 0x60u && ew <= 0x90u);
    int isbf = ((int)__popcll(bl) * 2 > 64) ? 1 : 0;

    int ra = r0 + m16;
    if (ra > n - 1) ra = n - 1;
    bf16x8 ah[4];
    if (isbf) {
        const int4* Xv = (const int4*)X;
        #pragma unroll
        for (int kt = 0; kt < 4; kt++)
            ah[kt] = __builtin_bit_cast(bf16x8, Xv[ra * 16 + kt * 4 + quad]);
    } else {
        const float4* Xf = (const float4*)X;
        #pragma unroll
        for (int kt = 0; kt < 4; kt++) {
            int jj = kt * 4 + quad;
            float4 fa = Xf[ra * 32 + jj * 2];
            float4 fb = Xf[ra * 32 + jj * 2 + 1];
            float v[8] = {fa.x, fa.y, fa.z, fa.w, fb.x, fb.y, fb.z, fb.w};
            bf16x8 h;
            #pragma unroll
            for (int j = 0; j < 8; j++) h[j] = (short)f2bf(v[j]);
            ah[kt] = h;
        }
    }

    float dv[4];
    #pragma unroll
    for (int reg = 0; reg < 4; reg++) {
        int row = r0 + quad * 4 + reg;
        if (row > n - 1) row = n - 1;
        dv[reg] = dinv[row];
    }

    const int4* Wvh = (const int4*)Wth;
    #pragma unroll
    for (int nt = 0; nt < 8; nt++) {
        f32x4 acc = {0.f, 0.f, 0.f, 0.f};
        int brow = (nt * 16 + m16) * 16;
        #pragma unroll
        for (int kt = 0; kt < 4; kt++) {
            bf16x8 bh = __builtin_bit_cast(bf16x8, Wvh[brow + kt * 4 + quad]);
            acc = __builtin_amdgcn_mfma_f32_16x16x32_bf16(ah[kt], bh, acc, 0, 0, 0);
        }
        #pragma unroll
        for (int reg = 0; reg < 4; reg++) {
            float v = acc[reg] * dv[reg];
            int pk = __builtin_amdgcn_cvt_pk_fp8_f32(v, v, 0, false);
            ldsrow[(quad * 4 + reg) * 128 + nt * 16 + m16] = (unsigned char)(pk & 0xFF);
        }
    }
    __syncthreads();
    const uint32_t* l32 = (const uint32_t*)ldsrow;
    #pragma unroll
    for (int i = 0; i < 8; i++) {
        int idx = i * 64 + l;
        int row = idx >> 5;
        int grow = r0 + row;
        if (grow < n) hs8[grow * 32 + (idx & 31)] = l32[idx];
    }
}

// ---- fused: scatter [0,SCB) || GEMM layer-1 [SCB,..) --------------------
__launch_bounds__(256)
__global__ void k_sg(const int* __restrict__ dstb, const int* __restrict__ srcb,
                     const int* __restrict__ bcnt,
                     int* __restrict__ cursor, int* __restrict__ col, int E,
                     const void* __restrict__ X,
                     const unsigned short* __restrict__ Wth,
                     const float* __restrict__ dinv,
                     uint32_t* __restrict__ hs8, int n) {
    __shared__ unsigned char lds8[4][16 * 128];
    int b = blockIdx.x;
    if (b < SCB) {
        int p = b & 7;
        int nb = SCB >> 3;
        int cnt = bcnt[p]; if (cnt > CAP) cnt = CAP;
        const int* db = dstb + p * CAP;
        const int* sb = srcb + p * CAP;
        for (int i = (b >> 3) * 256 + threadIdx.x; i < cnt; i += nb * 256) {
            int pos = atomicAdd(&cursor[db[i]], 1);
            if ((unsigned)pos < (unsigned)E) col[pos] = sb[i];
        }
        return;
    }
    int wave = threadIdx.x >> 6;
    int l = threadIdx.x & 63;
    gemm_body(X, Wth, dinv, hs8, n, (b - SCB) * 4 + wave, l, lds8[wave]);
}

// ---- fused agg-1 + GEMM-2: block owns 16 nodes --------------------------
// Phase A (r4 structure, r7 gather width): 4 waves x 4 sequential nodes.
//   QUAD-ROW int2 gather: lane = edge-slot (lane>>4, 0..3) x int2-quad
//   (lane&15); one VMEM fetches FOUR 128B rows (8B/lane). Per 16-edge
//   round: 4 col + 4 gather VMEMs (was 8+8 dword-pair) -- r5 showed the
//   phase is VMEM-instruction-count bound. Masked tail round kept from r4.
// Phase B: 16-row MFMA tile vs Wth2; each wave 2 nt-slices; fp8 pack+store.
__launch_bounds__(256)
__global__ void k_agg1gemm2(const unsigned short* __restrict__ hsv,
                            const int* __restrict__ row_ptr,
                            const int* __restrict__ col,
                            const float* __restrict__ dinv,
                            const float* __restrict__ bias,
                            const unsigned short* __restrict__ Wth2,
                            uint32_t* __restrict__ hs8out, int n, int E) {
    __shared__ __align__(16) unsigned short actlds[16 * 136]; // stride 136: bank-safe
    __shared__ unsigned char pack[16 * 128];
    int wave = threadIdx.x >> 6;
    int lane = threadIdx.x & 63;
    int q16 = lane & 15;          // int2-quad within row (0..15)
    int slot = lane >> 4;         // edge slot (0..3)
    int tile0 = blockIdx.x * 16;
    const int2* hsw2 = (const int2*)hsv;   // row = 16 int2 (128 fp8)

    // hoisted independent loads: 5 row_ptr + 4 self rows, all in flight
    int base_node = tile0 + wave * 4;
    int rp[5];
    #pragma unroll
    for (int k = 0; k < 5; k++) {
        int nn = base_node + k;
        if (nn > n) nn = n;
        rp[k] = row_ptr[nn];
    }
    int nd4[4]; int2 selfw4[4];
    #pragma unroll
    for (int k = 0; k < 4; k++) {
        int node = base_node + k;
        nd4[k] = (node < n) ? node : 0;
        selfw4[k] = hsw2[nd4[k] * 16 + q16];
    }

    // Phase A: aggregation (hs pre-scaled by dinv[src]; apply dinv[d]+bias+relu)
    #pragma unroll
    for (int i = 0; i < 4; i++) {
        int node = base_node + i;
        bool active = (node < n);
        int nd = nd4[i];

        int e = rp[i];
        int end = active ? rp[i + 1] : e;
        if (e < 0) e = 0;
        if (end > E) end = E;
        if (end < e) end = e;

        float a[8];
        #pragma unroll
        for (int j = 0; j < 8; j++) a[j] = 0.f;
        acc8(selfw4[i], (slot == 0) ? 1.0f : 0.0f, a);   // self counted once

        for (; e + 16 <= end; e += 16) {
            int2 uu[4];
            #pragma unroll
            for (int j = 0; j < 4; j++) {
                unsigned s = (unsigned)col[e + 4 * j + slot];
                if (s >= (unsigned)n) s = 0;
                uu[j] = hsw2[s * 16 + q16];
            }
            #pragma unroll
            for (int j = 0; j < 4; j++) acc8(uu[j], 1.0f, a);
        }
        if (e < end) {                      // ONE masked round covers the tail
            int2 uu[4];
            #pragma unroll
            for (int j = 0; j < 4; j++) {
                int ej = e + 4 * j + slot;
                int ec = (ej < end) ? ej : (end - 1);
                unsigned s = (unsigned)col[ec];
                if (s >= (unsigned)n) s = 0;
                uu[j] = hsw2[s * 16 + q16];
            }
            #pragma unroll
            for (int j = 0; j < 4; j++) {
                float m = ((e + 4 * j + slot) < end) ? 1.0f : 0.0f;
                acc8(uu[j], m, a);
            }
        }
        // combine the 4 edge-slots (xor bits 4,5; q16 = bits 0-3 preserved)
        #pragma unroll
        for (int j = 0; j < 8; j++) {
            a[j] += __shfl_xor(a[j], 16, 64);
            a[j] += __shfl_xor(a[j], 32, 64);
        }

        if (slot == 0) {   // lanes 0..15 hold features [8*q16, 8*q16+8)
            float dv = dinv[nd];
            const float4* b4 = (const float4*)bias;
            float4 b0 = b4[2 * q16];
            float4 b1q = b4[2 * q16 + 1];
            float r0 = fmaxf(dv * a[0] + b0.x, 0.f);
            float r1 = fmaxf(dv * a[1] + b0.y, 0.f);
            float r2 = fmaxf(dv * a[2] + b0.z, 0.f);
            float r3 = fmaxf(dv * a[3] + b0.w, 0.f);
            float r4 = fmaxf(dv * a[4] + b1q.x, 0.f);
            float r5 = fmaxf(dv * a[5] + b1q.y, 0.f);
            float r6 = fmaxf(dv * a[6] + b1q.z, 0.f);
            float r7 = fmaxf(dv * a[7] + b1q.w, 0.f);
            if (!active) { r0=0.f;r1=0.f;r2=0.f;r3=0.f;r4=0.f;r5=0.f;r6=0.f;r7=0.f; }
            int row = wave * 4 + i;
            uint4 w;
            w.x = (uint32_t)f2bf(r0) | ((uint32_t)f2bf(r1) << 16);
            w.y = (uint32_t)f2bf(r2) | ((uint32_t)f2bf(r3) << 16);
            w.z = (uint32_t)f2bf(r4) | ((uint32_t)f2bf(r5) << 16);
            w.w = (uint32_t)f2bf(r6) | ((uint32_t)f2bf(r7) << 16);
            *(uint4*)&actlds[row * 136 + 8 * q16] = w;   // byte 272*row+16*q16
        }
    }
    __syncthreads();

    // Phase B: MFMA tile (A from actlds; 16B-aligned: 136*2=272=16*17)
    int quad = lane >> 4;
    int m16 = lane & 15;
    bf16x8 ah[4];
    #pragma unroll
    for (int kt = 0; kt < 4; kt++) {
        const unsigned short* p = &actlds[m16 * 136 + kt * 32 + quad * 8];
        ah[kt] = __builtin_bit_cast(bf16x8, *(const int4*)p);
    }
    float dv4[4];
    #pragma unroll
    for (int reg = 0; reg < 4; reg++) {
        int row = tile0 + quad * 4 + reg;
        if (row > n - 1) row = n - 1;
        dv4[reg] = dinv[row];
    }
    const int4* Wvh = (const int4*)Wth2;
    #pragma unroll
    for (int ntl = 0; ntl < 2; ntl++) {
        int nt = wave * 2 + ntl;
        f32x4 acc = {0.f, 0.f, 0.f, 0.f};
        int brow = (nt * 16 + m16) * 16;
        #pragma unroll
        for (int kt = 0; kt < 4; kt++) {
            bf16x8 bh = __builtin_bit_cast(bf16x8, Wvh[brow + kt * 4 + quad]);
            acc = __builtin_amdgcn_mfma_f32_16x16x32_bf16(ah[kt], bh, acc, 0, 0, 0);
        }
        #pragma unroll
        for (int reg = 0; reg < 4; reg++) {
            float v = acc[reg] * dv4[reg];
            int pk = __builtin_amdgcn_cvt_pk_fp8_f32(v, v, 0, false);
            pack[(quad * 4 + reg) * 128 + nt * 16 + m16] = (unsigned char)(pk & 0xFF);
        }
    }
    __syncthreads();
    const uint32_t* l32 = (const uint32_t*)pack;
    #pragma unroll
    for (int i = 0; i < 2; i++) {
        int idx = i * 256 + threadIdx.x;   // 0..511
        int row = idx >> 5;
        int grow = tile0 + row;
        if (grow < n) hs8out[grow * 32 + (idx & 31)] = l32[idx];
    }
}

// ---- Pull aggregation layer-2 (fp8 hs, pre-scaled) -> pooled partials ---
// Quad-row int2 gather + single masked tail round (same as agg1gemm2).
__launch_bounds__(256)
__global__ void k_agg(const unsigned short* __restrict__ hsv,
                      const int* __restrict__ row_ptr,
                      const int* __restrict__ col, const float* __restrict__ dinv,
                      const float* __restrict__ bias,
                      float* __restrict__ partial, int n, int E) {
    __shared__ __align__(16) float pl[4][128];
    int wave = threadIdx.x >> 6;
    int lane = threadIdx.x & 63;
    int q16 = lane & 15;
    int slot = lane >> 4;
    int node = blockIdx.x * 4 + wave;
    bool active = (node < n);
    int nd = active ? node : 0;
    const int2* hsw2 = (const int2*)hsv;

    int2 selfw = hsw2[nd * 16 + q16];
    int e = row_ptr[nd];
    int end = active ? row_ptr[nd + 1] : e;
    if (e < 0) e = 0;
    if (end > E) end = E;
    if (end < e) end = e;

    float a[8];
    #pragma unroll
    for (int j = 0; j < 8; j++) a[j] = 0.f;
    acc8(selfw, (slot == 0) ? 1.0f : 0.0f, a);

    for (; e + 16 <= end; e += 16) {
        int2 uu[4];
        #pragma unroll
        for (int j = 0; j < 4; j++) {
            unsigned s = (unsigned)col[e + 4 * j + slot];
            if (s >= (unsigned)n) s = 0;
            uu[j] = hsw2[s * 16 + q16];
        }
        #pragma unroll
        for (int j = 0; j < 4; j++) acc8(uu[j], 1.0f, a);
    }
    if (e < end) {                          // ONE masked round covers the tail
        int2 uu[4];
        #pragma unroll
        for (int j = 0; j < 4; j++) {
            int ej = e + 4 * j + slot;
            int ec = (ej < end) ? ej : (end - 1);
            unsigned s = (unsigned)col[ec];
            if (s >= (unsigned)n) s = 0;
            uu[j] = hsw2[s * 16 + q16];
        }
        #pragma unroll
        for (int j = 0; j < 4; j++) {
            float m = ((e + 4 * j + slot) < end) ? 1.0f : 0.0f;
            acc8(uu[j], m, a);
        }
    }
    #pragma unroll
    for (int j = 0; j < 8; j++) {
        a[j] += __shfl_xor(a[j], 16, 64);
        a[j] += __shfl_xor(a[j], 32, 64);
    }

    if (slot == 0) {       // lanes 0..15: features [8*q16, 8*q16+8)
        float dv = dinv[nd];
        const float4* b4 = (const float4*)bias;
        float4 b0 = b4[2 * q16];
        float4 b1q = b4[2 * q16 + 1];
        float4 ra, rb;
        ra.x = fmaxf(dv * a[0] + b0.x, 0.f);
        ra.y = fmaxf(dv * a[1] + b0.y, 0.f);
        ra.z = fmaxf(dv * a[2] + b0.z, 0.f);
        ra.w = fmaxf(dv * a[3] + b0.w, 0.f);
        rb.x = fmaxf(dv * a[4] + b1q.x, 0.f);
        rb.y = fmaxf(dv * a[5] + b1q.y, 0.f);
        rb.z = fmaxf(dv * a[6] + b1q.z, 0.f);
        rb.w = fmaxf(dv * a[7] + b1q.w, 0.f);
        if (!active) {
            ra.x=0.f;ra.y=0.f;ra.z=0.f;ra.w=0.f;
            rb.x=0.f;rb.y=0.f;rb.z=0.f;rb.w=0.f;
        }
        *(float4*)&pl[wave][8 * q16]     = ra;   // byte 32*q16 (16B aligned)
        *(float4*)&pl[wave][8 * q16 + 4] = rb;
    }
    __syncthreads();
    int t = threadIdx.x;
    if (t < 128) {
        float ps = pl[0][t] + pl[1][t] + pl[2][t] + pl[3][t];
        partial[blockIdx.x * 128 + t] = ps;
    }
}

// ---- fused pooled reduce + FC (last-block pattern) ----------------------
__launch_bounds__(256)
__global__ void k_redfinal(const float* __restrict__ partial, float* __restrict__ pooled,
                           int* __restrict__ done,
                           const float* __restrict__ Wfcf, const float* __restrict__ bfcf,
                           const void* __restrict__ x, void* __restrict__ out,
                           int n, int nbrows, int gblocks) {
    __shared__ float red[8][128];
    int t = threadIdx.x;
    int chunk = (nbrows + gblocks - 1) / gblocks;
    int r0 = blockIdx.x * chunk;
    int r1 = r0 + chunk;
    if (r1 > nbrows) r1 = nbrows;

    float4 acc = {0.f, 0.f, 0.f, 0.f};
    const float4* p4 = (const float4*)partial;
    for (int i = r0 * 32 + t; i < r1 * 32; i += 256) {
        float4 v = p4[i];
        acc.x += v.x; acc.y += v.y; acc.z += v.z; acc.w += v.w;
    }
    int g = t >> 5;
    int fb = (t & 31) * 4;
    red[g][fb]     = acc.x;
    red[g][fb + 1] = acc.y;
    red[g][fb + 2] = acc.z;
    red[g][fb + 3] = acc.w;
    __syncthreads();
    if (t < 128) {
        float s = red[0][t] + red[1][t] + red[2][t] + red[3][t]
                + red[4][t] + red[5][t] + red[6][t] + red[7][t];
        atomicAdd(&pooled[t], s);
    }
    __threadfence();
    __shared__ int lastf;
    if (t == 0) lastf = (atomicAdd(done, 1) == gblocks - 1) ? 1 : 0;
    __syncthreads();
    if (!lastf) return;

    __shared__ int hits;
    __shared__ float pv[128];
    if (t == 0) hits = 0;
    __syncthreads();
    unsigned ew = (((const uint32_t*)x)[t] >> 7) & 0xFFu;
    unsigned long long bl = __ballot(ew >= 0x60u && ew <= 0x90u);
    if ((t & 63) == 0) atomicAdd(&hits, (int)__popcll(bl));
    if (t < 128)
        pv[t] = __hip_atomic_load(&pooled[t], __ATOMIC_RELAXED,
                                  __HIP_MEMORY_SCOPE_AGENT);
    __syncthreads();
    int isbf = (2 * hits > 256);
    if (t < 32) {
        float s = 0.f;
        for (int c = 0; c < 128; ++c) s += pv[c] * Wfcf[c * 32 + t];
        s = s * (1.0f / (float)n) + bfcf[t];
        if (isbf) ((unsigned short*)out)[t] = f2bf(s);
        else      ((float*)out)[t] = s;
    }
}

// ---- Launch -------------------------------------------------------------

extern "C" void kernel_launch(void* const* d_in, const int* in_sizes, int n_in,
                              void* d_out, int out_size, void* d_ws, size_t ws_size,
                              hipStream_t stream) {
    const void* x   = d_in[0];
    const int*  ei  = (const int*)d_in[1];
    const void* W1  = d_in[2];
    const void* b1  = d_in[3];
    const void* W2  = d_in[4];
    const void* b2  = d_in[5];
    const void* Wfc = d_in[6];
    const void* bfc = d_in[7];

    const int n = in_sizes[0] / FEAT;    // 50000
    const int E = in_sizes[1] / 2;       // 800000
    const int nagg = (n + 3) / 4;        // 12500
    const int ntile = (n + 15) / 16;     // 3125
    const int psz  = (n + 7) / 8;        // 6250
    const int nscan = (n + 255) / 256;   // 196
    const int NE   = (E + ECH - 1) / ECH;// 391
    const int gemm_grid = (ntile + 3) / 4; // 782

    char* ws = (char*)d_ws;
    uint32_t*       hs8     = (uint32_t*)(ws);                     // 6.4MB used
    uint32_t*       hs8b    = (uint32_t*)(ws + 12800000);          // 6.4MB (layer-2 hs)
    float*          partial = (float*)(ws + 25600000);             // 6.4MB used
    int*            col     = (int*)(ws + 38400000);               // 3.2MB
    int*            dstb    = (int*)(ws + 41600000);               // 6.4MB (8*CAP)
    int*            srcb    = (int*)(ws + 48000000);               // 6.4MB
    int*            deg     = (int*)(ws + 54400000);               // 200,000
    int*            row_ptr = (int*)(ws + 54600000);               // 200,016
    int*            cursor  = (int*)(ws + 54800016);               // 200,000
    float*          dinv    = (float*)(ws + 55000016);             // 200,000
    unsigned short* Wth1    = (unsigned short*)(ws + 55200016);    // 32,768
    unsigned short* Wth2    = (unsigned short*)(ws + 55232784);    // 32,768
    float*          b1f     = (float*)(ws + 55265552);             // 512
    float*          b2f     = (float*)(ws + 55266064);             // 512
    float*          Wfcf    = (float*)(ws + 55266576);             // 16,384
    float*          bfcf    = (float*)(ws + 55282960);             // 128
    // zero region (one memset): pooled | bcnt | done(+pad) | bsum
    float*          pooled  = (float*)(ws + 55283088);             // 512
    int*            bcnt    = (int*)(ws + 55283600);               // 32
    int*            done    = (int*)(ws + 55283632);               // 4 (+12 pad)
    int*            bsum    = (int*)(ws + 55283648);               // 784

    if (ws_size < 55284448) return;  // diagnostic: zero output => ws too small

    hipMemsetAsync(pooled, 0, 1344, stream);

    // 1) fused prep: edge decode+bucket (+deg zero) | weight/bias prep
    k_prep<<<NE + 82, 256, 0, stream>>>(ei, dstb, srcb, bcnt, deg, E, n, psz, NE,
                                        W1, W2, b1, b2, Wfc, bfc,
                                        Wth1, Wth2, b1f, b2f, Wfcf, bfcf);
    // 2) CSR: degree -> scan (boundaries are the cheap sync -- R11)
    k_degp<<<512, 256, 0, stream>>>(dstb, bcnt, deg);
    k_bsum<<<nscan, 256, 0, stream>>>(deg, bsum, dinv, n);
    k_bapply2<<<nscan, 256, 0, stream>>>(deg, bsum, row_ptr, cursor, n, nscan);
    // 3) fused: scatter || GEMM layer-1 (both dep only on bapply)
    k_sg<<<SCB + gemm_grid, 256, 0, stream>>>(dstb, srcb, bcnt, cursor, col, E,
                                              x, Wth1, dinv, hs8, n);
    // 4) fused agg-1 + GEMM-2 (r4 structure, int2 quad-row gather)
    k_agg1gemm2<<<ntile, 256, 0, stream>>>((const unsigned short*)hs8, row_ptr,
                                           col, dinv, b1f, Wth2, hs8b, n, E);
    // 5) agg-2 -> pooled partials (int2 quad-row gather)
    k_agg<<<nagg, 256, 0, stream>>>((const unsigned short*)hs8b, row_ptr, col,
                                    dinv, b2f, partial, n, E);
    // 6) fused pooled-reduce + FC
    k_redfinal<<<100, 256, 0, stream>>>(partial, pooled, done, Wfcf, bfcf,
                                        x, d_out, n, nagg, 100);
}

// Round 8
// 259.660 us; speedup vs baseline: 1.0357x; 1.0109x over previous
//
#include <hip/hip_runtime.h>
#include <stdint.h>

#define FEAT 128
#define ECH 2048   // edges per econv block
#define SCB 512    // scatter blocks in fused k_sg

typedef short bf16x8 __attribute__((ext_vector_type(8)));
typedef float f32x4 __attribute__((ext_vector_type(4)));
typedef float f32x2 __attribute__((ext_vector_type(2)));

__device__ __forceinline__ float bfs(unsigned short u) {
    uint32_t t = ((uint32_t)u) << 16;
    return __builtin_bit_cast(float, t);
}
__device__ __forceinline__ unsigned short f2bf(float f) {
    uint32_t u = __builtin_bit_cast(uint32_t, f);
    u += 0x7fffu + ((u >> 16) & 1u);
    return (unsigned short)(u >> 16);
}

// accumulate one int2 (8 fp8 features) into a[8] with mask m
__device__ __forceinline__ void acc8(int2 u, float m, float* a) {
    f32x2 t;
    t = __builtin_amdgcn_cvt_pk_f32_fp8(u.x, false);
    a[0] = fmaf(m, t.x, a[0]); a[1] = fmaf(m, t.y, a[1]);
    t = __builtin_amdgcn_cvt_pk_f32_fp8(u.x, true);
    a[2] = fmaf(m, t.x, a[2]); a[3] = fmaf(m, t.y, a[3]);
    t = __builtin_amdgcn_cvt_pk_f32_fp8(u.y, false);
    a[4] = fmaf(m, t.x, a[4]); a[5] = fmaf(m, t.y, a[5]);
    t = __builtin_amdgcn_cvt_pk_f32_fp8(u.y, true);
    a[6] = fmaf(m, t.x, a[6]); a[7] = fmaf(m, t.y, a[7]);
}

// ---- fused prep: econv blocks [0,NE) | W blocks [NE,NE+64) | bias [+18) -
// r8: de-staged CSR build. Device atomics execute at the coherence point
// regardless of dst partitioning (XCD L2s non-coherent), so the LDS
// bucketing + partitioned dstb/srcb + separate k_degp pass bought nothing
// for the atomic side. Flat stage + direct deg atomicAdd; k_degp deleted.
__launch_bounds__(256)
__global__ void k_prep(const int* __restrict__ ei,
                       int* __restrict__ dstb, int* __restrict__ srcb,
                       int* __restrict__ deg,
                       int E, int n, int NE,
                       const void* W1, const void* W2,
                       const void* b1, const void* b2,
                       const void* Wfc, const void* bfc,
                       unsigned short* Wth1, unsigned short* Wth2,
                       float* b1f, float* b2f, float* Wfcf, float* bfcf) {
    int t = threadIdx.x;

    if ((int)blockIdx.x >= NE) {
        __shared__ int hits;
        int blk = blockIdx.x - NE;
        const void* sampsrc = (blk < 32) ? W1 : (blk < 64 ? W2 : Wfc);
        const uint32_t* samp = (const uint32_t*)sampsrc;
        if (t == 0) hits = 0;
        __syncthreads();
        unsigned ew = (samp[t] >> 7) & 0xFFu;
        unsigned long long bl = __ballot(ew >= 0x60u && ew <= 0x90u);
        if ((t & 63) == 0) atomicAdd(&hits, (int)__popcll(bl));
        __syncthreads();
        int isbf = (2 * hits > 256);

        if (blk < 64) {
            const void* W = (blk < 32) ? W1 : W2;
            unsigned short* th = (blk < 32) ? Wth1 : Wth2;
            int base = (blk & 31) * 512;
            #pragma unroll
            for (int j = 0; j < 2; j++) {
                int idx = base + t * 2 + j;
                int nn = idx >> 7, k = idx & 127;
                int si = k * 128 + nn;
                float f = isbf ? bfs(((const unsigned short*)W)[si])
                               : ((const float*)W)[si];
                th[nn * 128 + k] = f2bf(f);
            }
        } else {
            int i = (blk - 64) * 256 + t;
            if (i >= 4384) return;
            const void* src; float* dst; int off;
            if (i < 128)       { src = b1;  dst = b1f;  off = i; }
            else if (i < 256)  { src = b2;  dst = b2f;  off = i - 128; }
            else if (i < 4352) { src = Wfc; dst = Wfcf; off = i - 256; }
            else               { src = bfc; dst = bfcf; off = i - 4352; }
            dst[off] = isbf ? bfs(((const unsigned short*)src)[off])
                            : ((const float*)src)[off];
        }
        return;
    }

    // ---- econv part: decode -> flat stage -> direct deg atomics ----
    __shared__ int lflag;
    if (t == 0) lflag = 0;
    __syncthreads();
    if (ei[1 + 2 * t] != 0) atomicOr(&lflag, 1);   // odd words: 0 => int64
    __syncthreads();
    int is32 = lflag;

    int base = blockIdx.x * ECH;
    #pragma unroll
    for (int j = 0; j < 8; j++) {
        int e = base + j * 256 + t;
        if (e < E) {
            int ss = is32 ? ei[e]     : ei[2 * e];
            int dd = is32 ? ei[E + e] : ei[2 * E + 2 * e];
            if ((unsigned)ss >= (unsigned)n) ss = 0;
            if ((unsigned)dd >= (unsigned)n) dd = 0;
            srcb[e] = ss;
            dstb[e] = dd;
            atomicAdd(&deg[dd], 1);
        }
    }
}

// ---- block sums (+ fused dinv) ------------------------------------------
__global__ void k_bsum(const int* __restrict__ deg, int* __restrict__ bsum,
                       float* __restrict__ dinv, int n) {
    __shared__ int ws[4];
    int t = threadIdx.x, lane = t & 63, w = t >> 6;
    int idx = blockIdx.x * 256 + t;
    int v = (idx < n) ? deg[idx] : 0;
    if (idx < n) dinv[idx] = rsqrtf((float)(v + 1));  // +1 self-loop
    int r = v;
    #pragma unroll
    for (int off = 32; off > 0; off >>= 1) r += __shfl_down(r, off, 64);
    if (lane == 0) ws[w] = r;
    __syncthreads();
    if (t == 0) bsum[blockIdx.x] = ws[0] + ws[1] + ws[2] + ws[3];
}

// ---- apply with self-computed block offset ------------------------------
__launch_bounds__(256)
__global__ void k_bapply2(const int* __restrict__ deg, const int* __restrict__ bsum,
                          int* __restrict__ row_ptr, int* __restrict__ cursor,
                          int n, int nb) {
    __shared__ int wred[4];
    __shared__ int wsum[4];
    __shared__ int boffs;
    int b = blockIdx.x, t = threadIdx.x, lane = t & 63, w = t >> 6;

    int pv = (t < b && t < nb) ? bsum[t] : 0;
    #pragma unroll
    for (int off = 32; off > 0; off >>= 1) pv += __shfl_down(pv, off, 64);
    if (lane == 0) wred[w] = pv;
    __syncthreads();
    if (t == 0) boffs = wred[0] + wred[1] + wred[2] + wred[3];
    __syncthreads();

    int idx = b * 256 + t;
    int v = (idx < n) ? deg[idx] : 0;
    int s = v;
    #pragma unroll
    for (int off = 1; off < 64; off <<= 1) {
        int x = __shfl_up(s, off, 64);
        if (lane >= off) s += x;
    }
    if (lane == 63) wsum[w] = s;
    __syncthreads();
    if (t == 0) {
        int acc = 0;
        #pragma unroll
        for (int i = 0; i < 4; i++) { int x = wsum[i]; wsum[i] = acc; acc += x; }
    }
    __syncthreads();
    int ex = boffs + s - v + wsum[w];
    if (idx < n) {
        row_ptr[idx] = ex;
        cursor[idx]  = ex;
    }
    if (idx == n - 1) row_ptr[n] = ex + v;
}

// ---- GEMM tile body: hs8 = fp8(dinv[row]*(X @ W)) -----------------------
__device__ __forceinline__ void gemm_body(const void* __restrict__ X,
                                          const unsigned short* __restrict__ Wth,
                                          const float* __restrict__ dinv,
                                          uint32_t* __restrict__ hs8,
                                          int n, int tile, int l,
                                          unsigned char* __restrict__ ldsrow) {
    int quad = l >> 4;
    int m16 = l & 15;
    int r0 = tile * 16;

    unsigned ew = (((const uint32_t*)X)[l] >> 7) & 0xFFu;
    unsigned long long bl = __ballot(ew >= 0x60u && ew <= 0x90u);
    int isbf = ((int)__popcll(bl) * 2 > 64) ? 1 : 0;

    int ra = r0 + m16;
    if (ra > n - 1) ra = n - 1;
    bf16x8 ah[4];
    if (isbf) {
        const int4* Xv = (const int4*)X;
        #pragma unroll
        for (int kt = 0; kt < 4; kt++)
            ah[kt] = __builtin_bit_cast(bf16x8, Xv[ra * 16 + kt * 4 + quad]);
    } else {
        const float4* Xf = (const float4*)X;
        #pragma unroll
        for (int kt = 0; kt < 4; kt++) {
            int jj = kt * 4 + quad;
            float4 fa = Xf[ra * 32 + jj * 2];
            float4 fb = Xf[ra * 32 + jj * 2 + 1];
            float v[8] = {fa.x, fa.y, fa.z, fa.w, fb.x, fb.y, fb.z, fb.w};
            bf16x8 h;
            #pragma unroll
            for (int j = 0; j < 8; j++) h[j] = (short)f2bf(v[j]);
            ah[kt] = h;
        }
    }

    float dv[4];
    #pragma unroll
    for (int reg = 0; reg < 4; reg++) {
        int row = r0 + quad * 4 + reg;
        if (row > n - 1) row = n - 1;
        dv[reg] = dinv[row];
    }

    const int4* Wvh = (const int4*)Wth;
    #pragma unroll
    for (int nt = 0; nt < 8; nt++) {
        f32x4 acc = {0.f, 0.f, 0.f, 0.f};
        int brow = (nt * 16 + m16) * 16;
        #pragma unroll
        for (int kt = 0; kt < 4; kt++) {
            bf16x8 bh = __builtin_bit_cast(bf16x8, Wvh[brow + kt * 4 + quad]);
            acc = __builtin_amdgcn_mfma_f32_16x16x32_bf16(ah[kt], bh, acc, 0, 0, 0);
        }
        #pragma unroll
        for (int reg = 0; reg < 4; reg++) {
            float v = acc[reg] * dv[reg];
            int pk = __builtin_amdgcn_cvt_pk_fp8_f32(v, v, 0, false);
            ldsrow[(quad * 4 + reg) * 128 + nt * 16 + m16] = (unsigned char)(pk & 0xFF);
        }
    }
    __syncthreads();
    const uint32_t* l32 = (const uint32_t*)ldsrow;
    #pragma unroll
    for (int i = 0; i < 8; i++) {
        int idx = i * 64 + l;
        int row = idx >> 5;
        int grow = r0 + row;
        if (grow < n) hs8[grow * 32 + (idx & 31)] = l32[idx];
    }
}

// ---- fused: scatter [0,SCB) || GEMM layer-1 [SCB,..) --------------------
__launch_bounds__(256)
__global__ void k_sg(const int* __restrict__ dstb, const int* __restrict__ srcb,
                     int* __restrict__ cursor, int* __restrict__ col, int E,
                     const void* __restrict__ X,
                     const unsigned short* __restrict__ Wth,
                     const float* __restrict__ dinv,
                     uint32_t* __restrict__ hs8, int n) {
    __shared__ unsigned char lds8[4][16 * 128];
    int b = blockIdx.x;
    if (b < SCB) {
        for (int i = b * 256 + threadIdx.x; i < E; i += SCB * 256) {
            int pos = atomicAdd(&cursor[dstb[i]], 1);
            if ((unsigned)pos < (unsigned)E) col[pos] = srcb[i];
        }
        return;
    }
    int wave = threadIdx.x >> 6;
    int l = threadIdx.x & 63;
    gemm_body(X, Wth, dinv, hs8, n, (b - SCB) * 4 + wave, l, lds8[wave]);
}

// ---- fused agg-1 + GEMM-2: block owns 16 nodes --------------------------
// Phase A (r4 structure, r7 gather width): 4 waves x 4 sequential nodes.
//   QUAD-ROW int2 gather: lane = edge-slot (lane>>4, 0..3) x int2-quad
//   (lane&15); one VMEM fetches FOUR 128B rows (8B/lane). Masked tail round.
// Phase B: 16-row MFMA tile vs Wth2; each wave 2 nt-slices; fp8 pack+store.
__launch_bounds__(256)
__global__ void k_agg1gemm2(const unsigned short* __restrict__ hsv,
                            const int* __restrict__ row_ptr,
                            const int* __restrict__ col,
                            const float* __restrict__ dinv,
                            const float* __restrict__ bias,
                            const unsigned short* __restrict__ Wth2,
                            uint32_t* __restrict__ hs8out, int n, int E) {
    __shared__ __align__(16) unsigned short actlds[16 * 136]; // stride 136: bank-safe
    __shared__ unsigned char pack[16 * 128];
    int wave = threadIdx.x >> 6;
    int lane = threadIdx.x & 63;
    int q16 = lane & 15;          // int2-quad within row (0..15)
    int slot = lane >> 4;         // edge slot (0..3)
    int tile0 = blockIdx.x * 16;
    const int2* hsw2 = (const int2*)hsv;   // row = 16 int2 (128 fp8)

    // hoisted independent loads: 5 row_ptr + 4 self rows, all in flight
    int base_node = tile0 + wave * 4;
    int rp[5];
    #pragma unroll
    for (int k = 0; k < 5; k++) {
        int nn = base_node + k;
        if (nn > n) nn = n;
        rp[k] = row_ptr[nn];
    }
    int nd4[4]; int2 selfw4[4];
    #pragma unroll
    for (int k = 0; k < 4; k++) {
        int node = base_node + k;
        nd4[k] = (node < n) ? node : 0;
        selfw4[k] = hsw2[nd4[k] * 16 + q16];
    }

    // Phase A: aggregation (hs pre-scaled by dinv[src]; apply dinv[d]+bias+relu)
    #pragma unroll
    for (int i = 0; i < 4; i++) {
        int node = base_node + i;
        bool active = (node < n);
        int nd = nd4[i];

        int e = rp[i];
        int end = active ? rp[i + 1] : e;
        if (e < 0) e = 0;
        if (end > E) end = E;
        if (end < e) end = e;

        float a[8];
        #pragma unroll
        for (int j = 0; j < 8; j++) a[j] = 0.f;
        acc8(selfw4[i], (slot == 0) ? 1.0f : 0.0f, a);   // self counted once

        for (; e + 16 <= end; e += 16) {
            int2 uu[4];
            #pragma unroll
            for (int j = 0; j < 4; j++) {
                unsigned s = (unsigned)col[e + 4 * j + slot];
                if (s >= (unsigned)n) s = 0;
                uu[j] = hsw2[s * 16 + q16];
            }
            #pragma unroll
            for (int j = 0; j < 4; j++) acc8(uu[j], 1.0f, a);
        }
        if (e < end) {                      // ONE masked round covers the tail
            int2 uu[4];
            #pragma unroll
            for (int j = 0; j < 4; j++) {
                int ej = e + 4 * j + slot;
                int ec = (ej < end) ? ej : (end - 1);
                unsigned s = (unsigned)col[ec];
                if (s >= (unsigned)n) s = 0;
                uu[j] = hsw2[s * 16 + q16];
            }
            #pragma unroll
            for (int j = 0; j < 4; j++) {
                float m = ((e + 4 * j + slot) < end) ? 1.0f : 0.0f;
                acc8(uu[j], m, a);
            }
        }
        // combine the 4 edge-slots (xor bits 4,5; q16 = bits 0-3 preserved)
        #pragma unroll
        for (int j = 0; j < 8; j++) {
            a[j] += __shfl_xor(a[j], 16, 64);
            a[j] += __shfl_xor(a[j], 32, 64);
        }

        if (slot == 0) {   // lanes 0..15 hold features [8*q16, 8*q16+8)
            float dv = dinv[nd];
            const float4* b4 = (const float4*)bias;
            float4 b0 = b4[2 * q16];
            float4 b1q = b4[2 * q16 + 1];
            float r0 = fmaxf(dv * a[0] + b0.x, 0.f);
            float r1 = fmaxf(dv * a[1] + b0.y, 0.f);
            float r2 = fmaxf(dv * a[2] + b0.z, 0.f);
            float r3 = fmaxf(dv * a[3] + b0.w, 0.f);
            float r4 = fmaxf(dv * a[4] + b1q.x, 0.f);
            float r5 = fmaxf(dv * a[5] + b1q.y, 0.f);
            float r6 = fmaxf(dv * a[6] + b1q.z, 0.f);
            float r7 = fmaxf(dv * a[7] + b1q.w, 0.f);
            if (!active) { r0=0.f;r1=0.f;r2=0.f;r3=0.f;r4=0.f;r5=0.f;r6=0.f;r7=0.f; }
            int row = wave * 4 + i;
            uint4 w;
            w.x = (uint32_t)f2bf(r0) | ((uint32_t)f2bf(r1) << 16);
            w.y = (uint32_t)f2bf(r2) | ((uint32_t)f2bf(r3) << 16);
            w.z = (uint32_t)f2bf(r4) | ((uint32_t)f2bf(r5) << 16);
            w.w = (uint32_t)f2bf(r6) | ((uint32_t)f2bf(r7) << 16);
            *(uint4*)&actlds[row * 136 + 8 * q16] = w;   // byte 272*row+16*q16
        }
    }
    __syncthreads();

    // Phase B: MFMA tile (A from actlds; 16B-aligned: 136*2=272=16*17)
    int quad = lane >> 4;
    int m16 = lane & 15;
    bf16x8 ah[4];
    #pragma unroll
    for (int kt = 0; kt < 4; kt++) {
        const unsigned short* p = &actlds[m16 * 136 + kt * 32 + quad * 8];
        ah[kt] = __builtin_bit_cast(bf16x8, *(const int4*)p);
    }
    float dv4[4];
    #pragma unroll
    for (int reg = 0; reg < 4; reg++) {
        int row = tile0 + quad * 4 + reg;
        if (row > n - 1) row = n - 1;
        dv4[reg] = dinv[row];
    }
    const int4* Wvh = (const int4*)Wth2;
    #pragma unroll
    for (int ntl = 0; ntl < 2; ntl++) {
        int nt = wave * 2 + ntl;
        f32x4 acc = {0.f, 0.f, 0.f, 0.f};
        int brow = (nt * 16 + m16) * 16;
        #pragma unroll
        for (int kt = 0; kt < 4; kt++) {
            bf16x8 bh = __builtin_bit_cast(bf16x8, Wvh[brow + kt * 4 + quad]);
            acc = __builtin_amdgcn_mfma_f32_16x16x32_bf16(ah[kt], bh, acc, 0, 0, 0);
        }
        #pragma unroll
        for (int reg = 0; reg < 4; reg++) {
            float v = acc[reg] * dv4[reg];
            int pk = __builtin_amdgcn_cvt_pk_fp8_f32(v, v, 0, false);
            pack[(quad * 4 + reg) * 128 + nt * 16 + m16] = (unsigned char)(pk & 0xFF);
        }
    }
    __syncthreads();
    const uint32_t* l32 = (const uint32_t*)pack;
    #pragma unroll
    for (int i = 0; i < 2; i++) {
        int idx = i * 256 + threadIdx.x;   // 0..511
        int row = idx >> 5;
        int grow = tile0 + row;
        if (grow < n) hs8out[grow * 32 + (idx & 31)] = l32[idx];
    }
}

// ---- Pull aggregation layer-2 (fp8 hs, pre-scaled) -> pooled partials ---
// Quad-row int2 gather + single masked tail round (same as agg1gemm2).
__launch_bounds__(256)
__global__ void k_agg(const unsigned short* __restrict__ hsv,
                      const int* __restrict__ row_ptr,
                      const int* __restrict__ col, const float* __restrict__ dinv,
                      const float* __restrict__ bias,
                      float* __restrict__ partial, int n, int E) {
    __shared__ __align__(16) float pl[4][128];
    int wave = threadIdx.x >> 6;
    int lane = threadIdx.x & 63;
    int q16 = lane & 15;
    int slot = lane >> 4;
    int node = blockIdx.x * 4 + wave;
    bool active = (node < n);
    int nd = active ? node : 0;
    const int2* hsw2 = (const int2*)hsv;

    int2 selfw = hsw2[nd * 16 + q16];
    int e = row_ptr[nd];
    int end = active ? row_ptr[nd + 1] : e;
    if (e < 0) e = 0;
    if (end > E) end = E;
    if (end < e) end = e;

    float a[8];
    #pragma unroll
    for (int j = 0; j < 8; j++) a[j] = 0.f;
    acc8(selfw, (slot == 0) ? 1.0f : 0.0f, a);

    for (; e + 16 <= end; e += 16) {
        int2 uu[4];
        #pragma unroll
        for (int j = 0; j < 4; j++) {
            unsigned s = (unsigned)col[e + 4 * j + slot];
            if (s >= (unsigned)n) s = 0;
            uu[j] = hsw2[s * 16 + q16];
        }
        #pragma unroll
        for (int j = 0; j < 4; j++) acc8(uu[j], 1.0f, a);
    }
    if (e < end) {                          // ONE masked round covers the tail
        int2 uu[4];
        #pragma unroll
        for (int j = 0; j < 4; j++) {
            int ej = e + 4 * j + slot;
            int ec = (ej < end) ? ej : (end - 1);
            unsigned s = (unsigned)col[ec];
            if (s >= (unsigned)n) s = 0;
            uu[j] = hsw2[s * 16 + q16];
        }
        #pragma unroll
        for (int j = 0; j < 4; j++) {
            float m = ((e + 4 * j + slot) < end) ? 1.0f : 0.0f;
            acc8(uu[j], m, a);
        }
    }
    #pragma unroll
    for (int j = 0; j < 8; j++) {
        a[j] += __shfl_xor(a[j], 16, 64);
        a[j] += __shfl_xor(a[j], 32, 64);
    }

    if (slot == 0) {       // lanes 0..15: features [8*q16, 8*q16+8)
        float dv = dinv[nd];
        const float4* b4 = (const float4*)bias;
        float4 b0 = b4[2 * q16];
        float4 b1q = b4[2 * q16 + 1];
        float4 ra, rb;
        ra.x = fmaxf(dv * a[0] + b0.x, 0.f);
        ra.y = fmaxf(dv * a[1] + b0.y, 0.f);
        ra.z = fmaxf(dv * a[2] + b0.z, 0.f);
        ra.w = fmaxf(dv * a[3] + b0.w, 0.f);
        rb.x = fmaxf(dv * a[4] + b1q.x, 0.f);
        rb.y = fmaxf(dv * a[5] + b1q.y, 0.f);
        rb.z = fmaxf(dv * a[6] + b1q.z, 0.f);
        rb.w = fmaxf(dv * a[7] + b1q.w, 0.f);
        if (!active) {
            ra.x=0.f;ra.y=0.f;ra.z=0.f;ra.w=0.f;
            rb.x=0.f;rb.y=0.f;rb.z=0.f;rb.w=0.f;
        }
        *(float4*)&pl[wave][8 * q16]     = ra;   // byte 32*q16 (16B aligned)
        *(float4*)&pl[wave][8 * q16 + 4] = rb;
    }
    __syncthreads();
    int t = threadIdx.x;
    if (t < 128) {
        float ps = pl[0][t] + pl[1][t] + pl[2][t] + pl[3][t];
        partial[blockIdx.x * 128 + t] = ps;
    }
}

// ---- fused pooled reduce + FC (last-block pattern) ----------------------
__launch_bounds__(256)
__global__ void k_redfinal(const float* __restrict__ partial, float* __restrict__ pooled,
                           int* __restrict__ done,
                           const float* __restrict__ Wfcf, const float* __restrict__ bfcf,
                           const void* __restrict__ x, void* __restrict__ out,
                           int n, int nbrows, int gblocks) {
    __shared__ float red[8][128];
    int t = threadIdx.x;
    int chunk = (nbrows + gblocks - 1) / gblocks;
    int r0 = blockIdx.x * chunk;
    int r1 = r0 + chunk;
    if (r1 > nbrows) r1 = nbrows;

    float4 acc = {0.f, 0.f, 0.f, 0.f};
    const float4* p4 = (const float4*)partial;
    for (int i = r0 * 32 + t; i < r1 * 32; i += 256) {
        float4 v = p4[i];
        acc.x += v.x; acc.y += v.y; acc.z += v.z; acc.w += v.w;
    }
    int g = t >> 5;
    int fb = (t & 31) * 4;
    red[g][fb]     = acc.x;
    red[g][fb + 1] = acc.y;
    red[g][fb + 2] = acc.z;
    red[g][fb + 3] = acc.w;
    __syncthreads();
    if (t < 128) {
        float s = red[0][t] + red[1][t] + red[2][t] + red[3][t]
                + red[4][t] + red[5][t] + red[6][t] + red[7][t];
        atomicAdd(&pooled[t], s);
    }
    __threadfence();
    __shared__ int lastf;
    if (t == 0) lastf = (atomicAdd(done, 1) == gblocks - 1) ? 1 : 0;
    __syncthreads();
    if (!lastf) return;

    __shared__ int hits;
    __shared__ float pv[128];
    if (t == 0) hits = 0;
    __syncthreads();
    unsigned ew = (((const uint32_t*)x)[t] >> 7) & 0xFFu;
    unsigned long long bl = __ballot(ew >= 0x60u && ew <= 0x90u);
    if ((t & 63) == 0) atomicAdd(&hits, (int)__popcll(bl));
    if (t < 128)
        pv[t] = __hip_atomic_load(&pooled[t], __ATOMIC_RELAXED,
                                  __HIP_MEMORY_SCOPE_AGENT);
    __syncthreads();
    int isbf = (2 * hits > 256);
    if (t < 32) {
        float s = 0.f;
        for (int c = 0; c < 128; ++c) s += pv[c] * Wfcf[c * 32 + t];
        s = s * (1.0f / (float)n) + bfcf[t];
        if (isbf) ((unsigned short*)out)[t] = f2bf(s);
        else      ((float*)out)[t] = s;
    }
}

// ---- Launch -------------------------------------------------------------

extern "C" void kernel_launch(void* const* d_in, const int* in_sizes, int n_in,
                              void* d_out, int out_size, void* d_ws, size_t ws_size,
                              hipStream_t stream) {
    const void* x   = d_in[0];
    const int*  ei  = (const int*)d_in[1];
    const void* W1  = d_in[2];
    const void* b1  = d_in[3];
    const void* W2  = d_in[4];
    const void* b2  = d_in[5];
    const void* Wfc = d_in[6];
    const void* bfc = d_in[7];

    const int n = in_sizes[0] / FEAT;    // 50000
    const int E = in_sizes[1] / 2;       // 800000
    const int nagg = (n + 3) / 4;        // 12500
    const int ntile = (n + 15) / 16;     // 3125
    const int nscan = (n + 255) / 256;   // 196
    const int NE   = (E + ECH - 1) / ECH;// 391
    const int gemm_grid = (ntile + 3) / 4; // 782

    char* ws = (char*)d_ws;
    uint32_t*       hs8     = (uint32_t*)(ws);                     // 6.4MB used
    uint32_t*       hs8b    = (uint32_t*)(ws + 12800000);          // 6.4MB (layer-2 hs)
    float*          partial = (float*)(ws + 25600000);             // 6.4MB used
    int*            col     = (int*)(ws + 38400000);               // 3.2MB
    int*            dstb    = (int*)(ws + 41600000);               // 3.2MB flat
    int*            srcb    = (int*)(ws + 48000000);               // 3.2MB flat
    int*            deg     = (int*)(ws + 54400000);               // 200,000
    int*            row_ptr = (int*)(ws + 54600000);               // 200,016
    int*            cursor  = (int*)(ws + 54800016);               // 200,000
    float*          dinv    = (float*)(ws + 55000016);             // 200,000
    unsigned short* Wth1    = (unsigned short*)(ws + 55200016);    // 32,768
    unsigned short* Wth2    = (unsigned short*)(ws + 55232784);    // 32,768
    float*          b1f     = (float*)(ws + 55265552);             // 512
    float*          b2f     = (float*)(ws + 55266064);             // 512
    float*          Wfcf    = (float*)(ws + 55266576);             // 16,384
    float*          bfcf    = (float*)(ws + 55282960);             // 128
    // zero region (one memset): pooled | (unused) | done(+pad) | bsum
    float*          pooled  = (float*)(ws + 55283088);             // 512
    int*            done    = (int*)(ws + 55283632);               // 4 (+12 pad)
    int*            bsum    = (int*)(ws + 55283648);               // 784

    if (ws_size < 55284448) return;  // diagnostic: zero output => ws too small

    hipMemsetAsync(pooled, 0, 1344, stream);
    hipMemsetAsync(deg, 0, (size_t)n * 4, stream);   // deg zero (r8: direct atomics)

    // 1) fused prep: edge decode + flat stage + direct deg atomics | W prep
    k_prep<<<NE + 82, 256, 0, stream>>>(ei, dstb, srcb, deg, E, n, NE,
                                        W1, W2, b1, b2, Wfc, bfc,
                                        Wth1, Wth2, b1f, b2f, Wfcf, bfcf);
    // 2) CSR scan (k_degp eliminated -- r8)
    k_bsum<<<nscan, 256, 0, stream>>>(deg, bsum, dinv, n);
    k_bapply2<<<nscan, 256, 0, stream>>>(deg, bsum, row_ptr, cursor, n, nscan);
    // 3) fused: scatter || GEMM layer-1 (both dep only on bapply)
    k_sg<<<SCB + gemm_grid, 256, 0, stream>>>(dstb, srcb, cursor, col, E,
                                              x, Wth1, dinv, hs8, n);
    // 4) fused agg-1 + GEMM-2 (r7 quad-row gather, unchanged)
    k_agg1gemm2<<<ntile, 256, 0, stream>>>((const unsigned short*)hs8, row_ptr,
                                           col, dinv, b1f, Wth2, hs8b, n, E);
    // 5) agg-2 -> pooled partials (unchanged)
    k_agg<<<nagg, 256, 0, stream>>>((const unsigned short*)hs8b, row_ptr, col,
                                    dinv, b2f, partial, n, E);
    // 6) fused pooled-reduce + FC
    k_redfinal<<<100, 256, 0, stream>>>(partial, pooled, done, Wfcf, bfcf,
                                        x, d_out, n, nagg, 100);
}

// Round 10
// 255.918 us; speedup vs baseline: 1.0508x; 1.0146x over previous
//
#include <hip/hip_runtime.h>
#include <stdint.h>

#define FEAT 128
#define ECH 2048   // edges per econv block
#define CAP 200000 // per-partition edge capacity
#define SCB 512    // scatter blocks in fused k_sg

typedef short bf16x8 __attribute__((ext_vector_type(8)));
typedef float f32x4 __attribute__((ext_vector_type(4)));
typedef float f32x2 __attribute__((ext_vector_type(2)));

__device__ __forceinline__ float bfs(unsigned short u) {
    uint32_t t = ((uint32_t)u) << 16;
    return __builtin_bit_cast(float, t);
}
__device__ __forceinline__ unsigned short f2bf(float f) {
    uint32_t u = __builtin_bit_cast(uint32_t, f);
    u += 0x7fffu + ((u >> 16) & 1u);
    return (unsigned short)(u >> 16);
}

// accumulate one int2 (8 fp8 features) into a[8] with mask m
__device__ __forceinline__ void acc8(int2 u, float m, float* a) {
    f32x2 t;
    t = __builtin_amdgcn_cvt_pk_f32_fp8(u.x, false);
    a[0] = fmaf(m, t.x, a[0]); a[1] = fmaf(m, t.y, a[1]);
    t = __builtin_amdgcn_cvt_pk_f32_fp8(u.x, true);
    a[2] = fmaf(m, t.x, a[2]); a[3] = fmaf(m, t.y, a[3]);
    t = __builtin_amdgcn_cvt_pk_f32_fp8(u.y, false);
    a[4] = fmaf(m, t.x, a[4]); a[5] = fmaf(m, t.y, a[5]);
    t = __builtin_amdgcn_cvt_pk_f32_fp8(u.y, true);
    a[6] = fmaf(m, t.x, a[6]); a[7] = fmaf(m, t.y, a[7]);
}

// ---- fused prep: econv blocks [0,NE) | W blocks [NE,NE+64) | bias [+18) -
// r9: partitioned bucketing RESTORED (r8 flat scatter caused 51MB write
// amplification: random 4B col writes from all XCDs dirty whole lines;
// b&7->XCD-pinned partitions let one L2 absorb them). k_degp stays deleted:
// deg atomicAdd fused into the decode loop (r8 win kept); deg zero = memset.
__launch_bounds__(256)
__global__ void k_prep(const int* __restrict__ ei,
                       int* __restrict__ dstb, int* __restrict__ srcb,
                       int* __restrict__ bcnt, int* __restrict__ deg,
                       int E, int n, int psz, int NE,
                       const void* W1, const void* W2,
                       const void* b1, const void* b2,
                       const void* Wfc, const void* bfc,
                       unsigned short* Wth1, unsigned short* Wth2,
                       float* b1f, float* b2f, float* Wfcf, float* bfcf) {
    int t = threadIdx.x;

    if ((int)blockIdx.x >= NE) {
        __shared__ int hits;
        int blk = blockIdx.x - NE;
        const void* sampsrc = (blk < 32) ? W1 : (blk < 64 ? W2 : Wfc);
        const uint32_t* samp = (const uint32_t*)sampsrc;
        if (t == 0) hits = 0;
        __syncthreads();
        unsigned ew = (samp[t] >> 7) & 0xFFu;
        unsigned long long bl = __ballot(ew >= 0x60u && ew <= 0x90u);
        if ((t & 63) == 0) atomicAdd(&hits, (int)__popcll(bl));
        __syncthreads();
        int isbf = (2 * hits > 256);

        if (blk < 64) {
            const void* W = (blk < 32) ? W1 : W2;
            unsigned short* th = (blk < 32) ? Wth1 : Wth2;
            int base = (blk & 31) * 512;
            #pragma unroll
            for (int j = 0; j < 2; j++) {
                int idx = base + t * 2 + j;
                int nn = idx >> 7, k = idx & 127;
                int si = k * 128 + nn;
                float f = isbf ? bfs(((const unsigned short*)W)[si])
                               : ((const float*)W)[si];
                th[nn * 128 + k] = f2bf(f);
            }
        } else {
            int i = (blk - 64) * 256 + t;
            if (i >= 4384) return;
            const void* src; float* dst; int off;
            if (i < 128)       { src = b1;  dst = b1f;  off = i; }
            else if (i < 256)  { src = b2;  dst = b2f;  off = i - 128; }
            else if (i < 4352) { src = Wfc; dst = Wfcf; off = i - 256; }
            else               { src = bfc; dst = bfcf; off = i - 4352; }
            dst[off] = isbf ? bfs(((const unsigned short*)src)[off])
                            : ((const float*)src)[off];
        }
        return;
    }

    // ---- econv part: decode -> deg atomics + partition-bucketed stage ----
    __shared__ int lflag;
    __shared__ int cnt[8], lofs[8], gbase[8];
    __shared__ int stage_s[ECH];
    __shared__ int stage_d[ECH];
    __shared__ char sb[ECH];
    if (t == 0) lflag = 0;
    if (t < 8) cnt[t] = 0;
    __syncthreads();
    if (ei[1 + 2 * t] != 0) atomicOr(&lflag, 1);   // odd words: 0 => int64
    __syncthreads();
    int is32 = lflag;

    int base = blockIdx.x * ECH;
    int s[8], d[8], p[8], slot[8];
    #pragma unroll
    for (int j = 0; j < 8; j++) {
        int e = base + j * 256 + t;
        int ss = 0, dd = 0;
        if (e < E) {
            ss = is32 ? ei[e]     : ei[2 * e];
            dd = is32 ? ei[E + e] : ei[2 * E + 2 * e];
            if ((unsigned)ss >= (unsigned)n) ss = 0;
            if ((unsigned)dd >= (unsigned)n) dd = 0;
            atomicAdd(&deg[dd], 1);            // r8: direct degree count
            int pp = dd / psz;
            if (pp > 7) pp = 7;
            p[j] = pp;
            slot[j] = atomicAdd(&cnt[pp], 1);
        } else p[j] = -1;
        s[j] = ss; d[j] = dd;
    }
    __syncthreads();
    if (t == 0) {
        int acc = 0;
        #pragma unroll
        for (int i = 0; i < 8; i++) { lofs[i] = acc; acc += cnt[i]; }
    }
    __syncthreads();
    if (t < 8) gbase[t] = atomicAdd(&bcnt[t], cnt[t]);
    __syncthreads();
    #pragma unroll
    for (int j = 0; j < 8; j++) {
        if (p[j] >= 0) {
            int pos = lofs[p[j]] + slot[j];
            stage_s[pos] = s[j];
            stage_d[pos] = d[j];
            sb[pos] = (char)p[j];
        }
    }
    __syncthreads();
    int tot = lofs[7] + cnt[7];
    for (int i = t; i < tot; i += 256) {
        int pp = sb[i];
        int off = gbase[pp] + (i - lofs[pp]);
        if (off < CAP) {
            dstb[pp * CAP + off] = stage_d[i];
            srcb[pp * CAP + off] = stage_s[i];
        }
    }
}

// ---- block sums (+ fused dinv) ------------------------------------------
__global__ void k_bsum(const int* __restrict__ deg, int* __restrict__ bsum,
                       float* __restrict__ dinv, int n) {
    __shared__ int ws[4];
    int t = threadIdx.x, lane = t & 63, w = t >> 6;
    int idx = blockIdx.x * 256 + t;
    int v = (idx < n) ? deg[idx] : 0;
    if (idx < n) dinv[idx] = rsqrtf((float)(v + 1));  // +1 self-loop
    int r = v;
    #pragma unroll
    for (int off = 32; off > 0; off >>= 1) r += __shfl_down(r, off, 64);
    if (lane == 0) ws[w] = r;
    __syncthreads();
    if (t == 0) bsum[blockIdx.x] = ws[0] + ws[1] + ws[2] + ws[3];
}

// ---- apply with self-computed block offset ------------------------------
__launch_bounds__(256)
__global__ void k_bapply2(const int* __restrict__ deg, const int* __restrict__ bsum,
                          int* __restrict__ row_ptr, int* __restrict__ cursor,
                          int n, int nb) {
    __shared__ int wred[4];
    __shared__ int wsum[4];
    __shared__ int boffs;
    int b = blockIdx.x, t = threadIdx.x, lane = t & 63, w = t >> 6;

    int pv = (t < b && t < nb) ? bsum[t] : 0;
    #pragma unroll
    for (int off = 32; off > 0; off >>= 1) pv += __shfl_down(pv, off, 64);
    if (lane == 0) wred[w] = pv;
    __syncthreads();
    if (t == 0) boffs = wred[0] + wred[1] + wred[2] + wred[3];
    __syncthreads();

    int idx = b * 256 + t;
    int v = (idx < n) ? deg[idx] : 0;
    int s = v;
    #pragma unroll
    for (int off = 1; off < 64; off <<= 1) {
        int x = __shfl_up(s, off, 64);
        if (lane >= off) s += x;
    }
    if (lane == 63) wsum[w] = s;
    __syncthreads();
    if (t == 0) {
        int acc = 0;
        #pragma unroll
        for (int i = 0; i < 4; i++) { int x = wsum[i]; wsum[i] = acc; acc += x; }
    }
    __syncthreads();
    int ex = boffs + s - v + wsum[w];
    if (idx < n) {
        row_ptr[idx] = ex;
        cursor[idx]  = ex;
    }
    if (idx == n - 1) row_ptr[n] = ex + v;
}

// ---- GEMM tile body: hs8 = fp8(dinv[row]*(X @ W)) -----------------------
__device__ __forceinline__ void gemm_body(const void* __restrict__ X,
                                          const unsigned short* __restrict__ Wth,
                                          const float* __restrict__ dinv,
                                          uint32_t* __restrict__ hs8,
                                          int n, int tile, int l,
                                          unsigned char* __restrict__ ldsrow) {
    int quad = l >> 4;
    int m16 = l & 15;
    int r0 = tile * 16;

    unsigned ew = (((const uint32_t*)X)[l] >> 7) & 0xFFu;
    unsigned long long bl = __ballot(ew >= 0x60u && ew <= 0x90u);
    int isbf = ((int)__popcll(bl) * 2 > 64) ? 1 : 0;

    int ra = r0 + m16;
    if (ra > n - 1) ra = n - 1;
    bf16x8 ah[4];
    if (isbf) {
        const int4* Xv = (const int4*)X;
        #pragma unroll
        for (int kt = 0; kt < 4; kt++)
            ah[kt] = __builtin_bit_cast(bf16x8, Xv[ra * 16 + kt * 4 + quad]);
    } else {
        const float4* Xf = (const float4*)X;
        #pragma unroll
        for (int kt = 0; kt < 4; kt++) {
            int jj = kt * 4 + quad;
            float4 fa = Xf[ra * 32 + jj * 2];
            float4 fb = Xf[ra * 32 + jj * 2 + 1];
            float v[8] = {fa.x, fa.y, fa.z, fa.w, fb.x, fb.y, fb.z, fb.w};
            bf16x8 h;
            #pragma unroll
            for (int j = 0; j < 8; j++) h[j] = (short)f2bf(v[j]);
            ah[kt] = h;
        }
    }

    float dv[4];
    #pragma unroll
    for (int reg = 0; reg < 4; reg++) {
        int row = r0 + quad * 4 + reg;
        if (row > n - 1) row = n - 1;
        dv[reg] = dinv[row];
    }

    const int4* Wvh = (const int4*)Wth;
    #pragma unroll
    for (int nt = 0; nt < 8; nt++) {
        f32x4 acc = {0.f, 0.f, 0.f, 0.f};
        int brow = (nt * 16 + m16) * 16;
        #pragma unroll
        for (int kt = 0; kt < 4; kt++) {
            bf16x8 bh = __builtin_bit_cast(bf16x8, Wvh[brow + kt * 4 + quad]);
            acc = __builtin_amdgcn_mfma_f32_16x16x32_bf16(ah[kt], bh, acc, 0, 0, 0);
        }
        #pragma unroll
        for (int reg = 0; reg < 4; reg++) {
            float v = acc[reg] * dv[reg];
            int pk = __builtin_amdgcn_cvt_pk_fp8_f32(v, v, 0, false);
            ldsrow[(quad * 4 + reg) * 128 + nt * 16 + m16] = (unsigned char)(pk & 0xFF);
        }
    }
    __syncthreads();
    const uint32_t* l32 = (const uint32_t*)ldsrow;
    #pragma unroll
    for (int i = 0; i < 8; i++) {
        int idx = i * 64 + l;
        int row = idx >> 5;
        int grow = r0 + row;
        if (grow < n) hs8[grow * 32 + (idx & 31)] = l32[idx];
    }
}

// ---- fused: scatter [0,SCB) || GEMM layer-1 [SCB,..) --------------------
// Scatter partitioned again (r9): b&7 = partition -> stable XCD -> its L2
// absorbs the random 4B col/cursor writes (r8 flat version: 51MB write amp).
__launch_bounds__(256)
__global__ void k_sg(const int* __restrict__ dstb, const int* __restrict__ srcb,
                     const int* __restrict__ bcnt,
                     int* __restrict__ cursor, int* __restrict__ col, int E,
                     const void* __restrict__ X,
                     const unsigned short* __restrict__ Wth,
                     const float* __restrict__ dinv,
                     uint32_t* __restrict__ hs8, int n) {
    __shared__ unsigned char lds8[4][16 * 128];
    int b = blockIdx.x;
    if (b < SCB) {
        int p = b & 7;
        int nb = SCB >> 3;
        int cnt = bcnt[p]; if (cnt > CAP) cnt = CAP;
        const int* db = dstb + p * CAP;
        const int* sb = srcb + p * CAP;
        for (int i = (b >> 3) * 256 + threadIdx.x; i < cnt; i += nb * 256) {
            int pos = atomicAdd(&cursor[db[i]], 1);
            if ((unsigned)pos < (unsigned)E) col[pos] = sb[i];
        }
        return;
    }
    int wave = threadIdx.x >> 6;
    int l = threadIdx.x & 63;
    gemm_body(X, Wth, dinv, hs8, n, (b - SCB) * 4 + wave, l, lds8[wave]);
}

// ---- fused agg-1 + GEMM-2: block owns 16 nodes --------------------------
// Phase A (r4 structure, r7 gather width): 4 waves x 4 sequential nodes.
//   QUAD-ROW int2 gather: lane = edge-slot (lane>>4, 0..3) x int2-quad
//   (lane&15); one VMEM fetches FOUR 128B rows (8B/lane). Masked tail round.
// Phase B: 16-row MFMA tile vs Wth2; each wave 2 nt-slices; fp8 pack+store.
__launch_bounds__(256)
__global__ void k_agg1gemm2(const unsigned short* __restrict__ hsv,
                            const int* __restrict__ row_ptr,
                            const int* __restrict__ col,
                            const float* __restrict__ dinv,
                            const float* __restrict__ bias,
                            const unsigned short* __restrict__ Wth2,
                            uint32_t* __restrict__ hs8out, int n, int E) {
    __shared__ __align__(16) unsigned short actlds[16 * 136]; // stride 136: bank-safe
    __shared__ unsigned char pack[16 * 128];
    int wave = threadIdx.x >> 6;
    int lane = threadIdx.x & 63;
    int q16 = lane & 15;          // int2-quad within row (0..15)
    int slot = lane >> 4;         // edge slot (0..3)
    int tile0 = blockIdx.x * 16;
    const int2* hsw2 = (const int2*)hsv;   // row = 16 int2 (128 fp8)

    // hoisted independent loads: 5 row_ptr + 4 self rows, all in flight
    int base_node = tile0 + wave * 4;
    int rp[5];
    #pragma unroll
    for (int k = 0; k < 5; k++) {
        int nn = base_node + k;
        if (nn > n) nn = n;
        rp[k] = row_ptr[nn];
    }
    int nd4[4]; int2 selfw4[4];
    #pragma unroll
    for (int k = 0; k < 4; k++) {
        int node = base_node + k;
        nd4[k] = (node < n) ? node : 0;
        selfw4[k] = hsw2[nd4[k] * 16 + q16];
    }

    // Phase A: aggregation (hs pre-scaled by dinv[src]; apply dinv[d]+bias+relu)
    #pragma unroll
    for (int i = 0; i < 4; i++) {
        int node = base_node + i;
        bool active = (node < n);
        int nd = nd4[i];

        int e = rp[i];
        int end = active ? rp[i + 1] : e;
        if (e < 0) e = 0;
        if (end > E) end = E;
        if (end < e) end = e;

        float a[8];
        #pragma unroll
        for (int j = 0; j < 8; j++) a[j] = 0.f;
        acc8(selfw4[i], (slot == 0) ? 1.0f : 0.0f, a);   // self counted once

        for (; e + 16 <= end; e += 16) {
            int2 uu[4];
            #pragma unroll
            for (int j = 0; j < 4; j++) {
                unsigned s = (unsigned)col[e + 4 * j + slot];
                if (s >= (unsigned)n) s = 0;
                uu[j] = hsw2[s * 16 + q16];
            }
            #pragma unroll
            for (int j = 0; j < 4; j++) acc8(uu[j], 1.0f, a);
        }
        if (e < end) {                      // ONE masked round covers the tail
            int2 uu[4];
            #pragma unroll
            for (int j = 0; j < 4; j++) {
                int ej = e + 4 * j + slot;
                int ec = (ej < end) ? ej : (end - 1);
                unsigned s = (unsigned)col[ec];
                if (s >= (unsigned)n) s = 0;
                uu[j] = hsw2[s * 16 + q16];
            }
            #pragma unroll
            for (int j = 0; j < 4; j++) {
                float m = ((e + 4 * j + slot) < end) ? 1.0f : 0.0f;
                acc8(uu[j], m, a);
            }
        }
        // combine the 4 edge-slots (xor bits 4,5; q16 = bits 0-3 preserved)
        #pragma unroll
        for (int j = 0; j < 8; j++) {
            a[j] += __shfl_xor(a[j], 16, 64);
            a[j] += __shfl_xor(a[j], 32, 64);
        }

        if (slot == 0) {   // lanes 0..15 hold features [8*q16, 8*q16+8)
            float dv = dinv[nd];
            const float4* b4 = (const float4*)bias;
            float4 b0 = b4[2 * q16];
            float4 b1q = b4[2 * q16 + 1];
            float r0 = fmaxf(dv * a[0] + b0.x, 0.f);
            float r1 = fmaxf(dv * a[1] + b0.y, 0.f);
            float r2 = fmaxf(dv * a[2] + b0.z, 0.f);
            float r3 = fmaxf(dv * a[3] + b0.w, 0.f);
            float r4 = fmaxf(dv * a[4] + b1q.x, 0.f);
            float r5 = fmaxf(dv * a[5] + b1q.y, 0.f);
            float r6 = fmaxf(dv * a[6] + b1q.z, 0.f);
            float r7 = fmaxf(dv * a[7] + b1q.w, 0.f);
            if (!active) { r0=0.f;r1=0.f;r2=0.f;r3=0.f;r4=0.f;r5=0.f;r6=0.f;r7=0.f; }
            int row = wave * 4 + i;
            uint4 w;
            w.x = (uint32_t)f2bf(r0) | ((uint32_t)f2bf(r1) << 16);
            w.y = (uint32_t)f2bf(r2) | ((uint32_t)f2bf(r3) << 16);
            w.z = (uint32_t)f2bf(r4) | ((uint32_t)f2bf(r5) << 16);
            w.w = (uint32_t)f2bf(r6) | ((uint32_t)f2bf(r7) << 16);
            *(uint4*)&actlds[row * 136 + 8 * q16] = w;   // byte 272*row+16*q16
        }
    }
    __syncthreads();

    // Phase B: MFMA tile (A from actlds; 16B-aligned: 136*2=272=16*17)
    int quad = lane >> 4;
    int m16 = lane & 15;
    bf16x8 ah[4];
    #pragma unroll
    for (int kt = 0; kt < 4; kt++) {
        const unsigned short* p = &actlds[m16 * 136 + kt * 32 + quad * 8];
        ah[kt] = __builtin_bit_cast(bf16x8, *(const int4*)p);
    }
    float dv4[4];
    #pragma unroll
    for (int reg = 0; reg < 4; reg++) {
        int row = tile0 + quad * 4 + reg;
        if (row > n - 1) row = n - 1;
        dv4[reg] = dinv[row];
    }
    const int4* Wvh = (const int4*)Wth2;
    #pragma unroll
    for (int ntl = 0; ntl < 2; ntl++) {
        int nt = wave * 2 + ntl;
        f32x4 acc = {0.f, 0.f, 0.f, 0.f};
        int brow = (nt * 16 + m16) * 16;
        #pragma unroll
        for (int kt = 0; kt < 4; kt++) {
            bf16x8 bh = __builtin_bit_cast(bf16x8, Wvh[brow + kt * 4 + quad]);
            acc = __builtin_amdgcn_mfma_f32_16x16x32_bf16(ah[kt], bh, acc, 0, 0, 0);
        }
        #pragma unroll
        for (int reg = 0; reg < 4; reg++) {
            float v = acc[reg] * dv4[reg];
            int pk = __builtin_amdgcn_cvt_pk_fp8_f32(v, v, 0, false);
            pack[(quad * 4 + reg) * 128 + nt * 16 + m16] = (unsigned char)(pk & 0xFF);
        }
    }
    __syncthreads();
    const uint32_t* l32 = (const uint32_t*)pack;
    #pragma unroll
    for (int i = 0; i < 2; i++) {
        int idx = i * 256 + threadIdx.x;   // 0..511
        int row = idx >> 5;
        int grow = tile0 + row;
        if (grow < n) hs8out[grow * 32 + (idx & 31)] = l32[idx];
    }
}

// ---- Pull aggregation layer-2 (fp8 hs, pre-scaled) -> pooled partials ---
// Quad-row int2 gather + single masked tail round (same as agg1gemm2).
__launch_bounds__(256)
__global__ void k_agg(const unsigned short* __restrict__ hsv,
                      const int* __restrict__ row_ptr,
                      const int* __restrict__ col, const float* __restrict__ dinv,
                      const float* __restrict__ bias,
                      float* __restrict__ partial, int n, int E) {
    __shared__ __align__(16) float pl[4][128];
    int wave = threadIdx.x >> 6;
    int lane = threadIdx.x & 63;
    int q16 = lane & 15;
    int slot = lane >> 4;
    int node = blockIdx.x * 4 + wave;
    bool active = (node < n);
    int nd = active ? node : 0;
    const int2* hsw2 = (const int2*)hsv;

    int2 selfw = hsw2[nd * 16 + q16];
    int e = row_ptr[nd];
    int end = active ? row_ptr[nd + 1] : e;
    if (e < 0) e = 0;
    if (end > E) end = E;
    if (end < e) end = e;

    float a[8];
    #pragma unroll
    for (int j = 0; j < 8; j++) a[j] = 0.f;
    acc8(selfw, (slot == 0) ? 1.0f : 0.0f, a);

    for (; e + 16 <= end; e += 16) {
        int2 uu[4];
        #pragma unroll
        for (int j = 0; j < 4; j++) {
            unsigned s = (unsigned)col[e + 4 * j + slot];
            if (s >= (unsigned)n) s = 0;
            uu[j] = hsw2[s * 16 + q16];
        }
        #pragma unroll
        for (int j = 0; j < 4; j++) acc8(uu[j], 1.0f, a);
    }
    if (e < end) {                          // ONE masked round covers the tail
        int2 uu[4];
        #pragma unroll
        for (int j = 0; j < 4; j++) {
            int ej = e + 4 * j + slot;
            int ec = (ej < end) ? ej : (end - 1);
            unsigned s = (unsigned)col[ec];
            if (s >= (unsigned)n) s = 0;
            uu[j] = hsw2[s * 16 + q16];
        }
        #pragma unroll
        for (int j = 0; j < 4; j++) {
            float m = ((e + 4 * j + slot) < end) ? 1.0f : 0.0f;
            acc8(uu[j], m, a);
        }
    }
    #pragma unroll
    for (int j = 0; j < 8; j++) {
        a[j] += __shfl_xor(a[j], 16, 64);
        a[j] += __shfl_xor(a[j], 32, 64);
    }

    if (slot == 0) {       // lanes 0..15: features [8*q16, 8*q16+8)
        float dv = dinv[nd];
        const float4* b4 = (const float4*)bias;
        float4 b0 = b4[2 * q16];
        float4 b1q = b4[2 * q16 + 1];
        float4 ra, rb;
        ra.x = fmaxf(dv * a[0] + b0.x, 0.f);
        ra.y = fmaxf(dv * a[1] + b0.y, 0.f);
        ra.z = fmaxf(dv * a[2] + b0.z, 0.f);
        ra.w = fmaxf(dv * a[3] + b0.w, 0.f);
        rb.x = fmaxf(dv * a[4] + b1q.x, 0.f);
        rb.y = fmaxf(dv * a[5] + b1q.y, 0.f);
        rb.z = fmaxf(dv * a[6] + b1q.z, 0.f);
        rb.w = fmaxf(dv * a[7] + b1q.w, 0.f);
        if (!active) {
            ra.x=0.f;ra.y=0.f;ra.z=0.f;ra.w=0.f;
            rb.x=0.f;rb.y=0.f;rb.z=0.f;rb.w=0.f;
        }
        *(float4*)&pl[wave][8 * q16]     = ra;   // byte 32*q16 (16B aligned)
        *(float4*)&pl[wave][8 * q16 + 4] = rb;
    }
    __syncthreads();
    int t = threadIdx.x;
    if (t < 128) {
        float ps = pl[0][t] + pl[1][t] + pl[2][t] + pl[3][t];
        partial[blockIdx.x * 128 + t] = ps;
    }
}

// ---- fused pooled reduce + FC (last-block pattern) ----------------------
__launch_bounds__(256)
__global__ void k_redfinal(const float* __restrict__ partial, float* __restrict__ pooled,
                           int* __restrict__ done,
                           const float* __restrict__ Wfcf, const float* __restrict__ bfcf,
                           const void* __restrict__ x, void* __restrict__ out,
                           int n, int nbrows, int gblocks) {
    __shared__ float red[8][128];
    int t = threadIdx.x;
    int chunk = (nbrows + gblocks - 1) / gblocks;
    int r0 = blockIdx.x * chunk;
    int r1 = r0 + chunk;
    if (r1 > nbrows) r1 = nbrows;

    float4 acc = {0.f, 0.f, 0.f, 0.f};
    const float4* p4 = (const float4*)partial;
    for (int i = r0 * 32 + t; i < r1 * 32; i += 256) {
        float4 v = p4[i];
        acc.x += v.x; acc.y += v.y; acc.z += v.z; acc.w += v.w;
    }
    int g = t >> 5;
    int fb = (t & 31) * 4;
    red[g][fb]     = acc.x;
    red[g][fb + 1] = acc.y;
    red[g][fb + 2] = acc.z;
    red[g][fb + 3] = acc.w;
    __syncthreads();
    if (t < 128) {
        float s = red[0][t] + red[1][t] + red[2][t] + red[3][t]
                + red[4][t] + red[5][t] + red[6][t] + red[7][t];
        atomicAdd(&pooled[t], s);
    }
    __threadfence();
    __shared__ int lastf;
    if (t == 0) lastf = (atomicAdd(done, 1) == gblocks - 1) ? 1 : 0;
    __syncthreads();
    if (!lastf) return;

    __shared__ int hits;
    __shared__ float pv[128];
    if (t == 0) hits = 0;
    __syncthreads();
    unsigned ew = (((const uint32_t*)x)[t] >> 7) & 0xFFu;
    unsigned long long bl = __ballot(ew >= 0x60u && ew <= 0x90u);
    if ((t & 63) == 0) atomicAdd(&hits, (int)__popcll(bl));
    if (t < 128)
        pv[t] = __hip_atomic_load(&pooled[t], __ATOMIC_RELAXED,
                                  __HIP_MEMORY_SCOPE_AGENT);
    __syncthreads();
    int isbf = (2 * hits > 256);
    if (t < 32) {
        float s = 0.f;
        for (int c = 0; c < 128; ++c) s += pv[c] * Wfcf[c * 32 + t];
        s = s * (1.0f / (float)n) + bfcf[t];
        if (isbf) ((unsigned short*)out)[t] = f2bf(s);
        else      ((float*)out)[t] = s;
    }
}

// ---- Launch -------------------------------------------------------------

extern "C" void kernel_launch(void* const* d_in, const int* in_sizes, int n_in,
                              void* d_out, int out_size, void* d_ws, size_t ws_size,
                              hipStream_t stream) {
    const void* x   = d_in[0];
    const int*  ei  = (const int*)d_in[1];
    const void* W1  = d_in[2];
    const void* b1  = d_in[3];
    const void* W2  = d_in[4];
    const void* b2  = d_in[5];
    const void* Wfc = d_in[6];
    const void* bfc = d_in[7];

    const int n = in_sizes[0] / FEAT;    // 50000
    const int E = in_sizes[1] / 2;       // 800000
    const int nagg = (n + 3) / 4;        // 12500
    const int ntile = (n + 15) / 16;     // 3125
    const int psz  = (n + 7) / 8;        // 6250
    const int nscan = (n + 255) / 256;   // 196
    const int NE   = (E + ECH - 1) / ECH;// 391
    const int gemm_grid = (ntile + 3) / 4; // 782

    char* ws = (char*)d_ws;
    uint32_t*       hs8     = (uint32_t*)(ws);                     // 6.4MB used
    uint32_t*       hs8b    = (uint32_t*)(ws + 12800000);          // 6.4MB (layer-2 hs)
    float*          partial = (float*)(ws + 25600000);             // 6.4MB used
    int*            col     = (int*)(ws + 38400000);               // 3.2MB
    int*            dstb    = (int*)(ws + 41600000);               // 6.4MB (8*CAP)
    int*            srcb    = (int*)(ws + 48000000);               // 6.4MB
    int*            deg     = (int*)(ws + 54400000);               // 200,000
    int*            row_ptr = (int*)(ws + 54600000);               // 200,016
    int*            cursor  = (int*)(ws + 54800016);               // 200,000
    float*          dinv    = (float*)(ws + 55000016);             // 200,000
    unsigned short* Wth1    = (unsigned short*)(ws + 55200016);    // 32,768
    unsigned short* Wth2    = (unsigned short*)(ws + 55232784);    // 32,768
    float*          b1f     = (float*)(ws + 55265552);             // 512
    float*          b2f     = (float*)(ws + 55266064);             // 512
    float*          Wfcf    = (float*)(ws + 55266576);             // 16,384
    float*          bfcf    = (float*)(ws + 55282960);             // 128
    // zero region (one memset): pooled | bcnt | done(+pad) | bsum
    float*          pooled  = (float*)(ws + 55283088);             // 512
    int*            bcnt    = (int*)(ws + 55283600);               // 32
    int*            done    = (int*)(ws + 55283632);               // 4 (+12 pad)
    int*            bsum    = (int*)(ws + 55283648);               // 784

    if (ws_size < 55284448) return;  // diagnostic: zero output => ws too small

    hipMemsetAsync(pooled, 0, 1344, stream);
    hipMemsetAsync(deg, 0, (size_t)n * 4, stream);   // deg zero (r8: direct atomics)

    // 1) fused prep: decode + deg atomics + partition bucketing | W prep
    k_prep<<<NE + 82, 256, 0, stream>>>(ei, dstb, srcb, bcnt, deg, E, n, psz, NE,
                                        W1, W2, b1, b2, Wfc, bfc,
                                        Wth1, Wth2, b1f, b2f, Wfcf, bfcf);
    // 2) CSR scan (k_degp eliminated -- r8)
    k_bsum<<<nscan, 256, 0, stream>>>(deg, bsum, dinv, n);
    k_bapply2<<<nscan, 256, 0, stream>>>(deg, bsum, row_ptr, cursor, n, nscan);
    // 3) fused: partitioned scatter || GEMM layer-1
    k_sg<<<SCB + gemm_grid, 256, 0, stream>>>(dstb, srcb, bcnt, cursor, col, E,
                                              x, Wth1, dinv, hs8, n);
    // 4) fused agg-1 + GEMM-2 (r7 quad-row gather, unchanged)
    k_agg1gemm2<<<ntile, 256, 0, stream>>>((const unsigned short*)hs8, row_ptr,
                                           col, dinv, b1f, Wth2, hs8b, n, E);
    // 5) agg-2 -> pooled partials (unchanged)
    k_agg<<<nagg, 256, 0, stream>>>((const unsigned short*)hs8b, row_ptr, col,
                                    dinv, b2f, partial, n, E);
    // 6) fused pooled-reduce + FC
    k_redfinal<<<100, 256, 0, stream>>>(partial, pooled, done, Wfcf, bfcf,
                                        x, d_out, n, nagg, 100);
}

// Round 11
// 252.898 us; speedup vs baseline: 1.0633x; 1.0119x over previous
//
#include <hip/hip_runtime.h>
#include <stdint.h>

#define FEAT 128
#define ECH 2048   // edges per econv block
#define CAP 200000 // per-partition edge capacity
#define SCB 512    // scatter blocks in fused k_sg

typedef short bf16x8 __attribute__((ext_vector_type(8)));
typedef float f32x4 __attribute__((ext_vector_type(4)));
typedef float f32x2 __attribute__((ext_vector_type(2)));

__device__ __forceinline__ float bfs(unsigned short u) {
    uint32_t t = ((uint32_t)u) << 16;
    return __builtin_bit_cast(float, t);
}
__device__ __forceinline__ unsigned short f2bf(float f) {
    uint32_t u = __builtin_bit_cast(uint32_t, f);
    u += 0x7fffu + ((u >> 16) & 1u);
    return (unsigned short)(u >> 16);
}

// accumulate one int2 (8 fp8 features) into a[8] with mask m
__device__ __forceinline__ void acc8(int2 u, float m, float* a) {
    f32x2 t;
    t = __builtin_amdgcn_cvt_pk_f32_fp8(u.x, false);
    a[0] = fmaf(m, t.x, a[0]); a[1] = fmaf(m, t.y, a[1]);
    t = __builtin_amdgcn_cvt_pk_f32_fp8(u.x, true);
    a[2] = fmaf(m, t.x, a[2]); a[3] = fmaf(m, t.y, a[3]);
    t = __builtin_amdgcn_cvt_pk_f32_fp8(u.y, false);
    a[4] = fmaf(m, t.x, a[4]); a[5] = fmaf(m, t.y, a[5]);
    t = __builtin_amdgcn_cvt_pk_f32_fp8(u.y, true);
    a[6] = fmaf(m, t.x, a[6]); a[7] = fmaf(m, t.y, a[7]);
}

// ---- fused prep: econv blocks [0,NE) | W blocks [NE,NE+64) | bias [+18) -
// r11: de-staged bucketing. Partition bucketing kept (r9 win: XCD-pinned
// scatter), but edges now write DIRECTLY to the partition bucket at
// gbase[p]+slot (per-block ~1KB chunk per partition -> L2-absorbed), not
// via a 24.5KB LDS staging round-trip. 2 barriers instead of 5. deg
// atomics stay fused (r8 win); deg zero via the single merged memset.
__launch_bounds__(256)
__global__ void k_prep(const int* __restrict__ ei,
                       int* __restrict__ dstb, int* __restrict__ srcb,
                       int* __restrict__ bcnt, int* __restrict__ deg,
                       int E, int n, int psz, int NE,
                       const void* W1, const void* W2,
                       const void* b1, const void* b2,
                       const void* Wfc, const void* bfc,
                       unsigned short* Wth1, unsigned short* Wth2,
                       float* b1f, float* b2f, float* Wfcf, float* bfcf) {
    int t = threadIdx.x;

    if ((int)blockIdx.x >= NE) {
        __shared__ int hits;
        int blk = blockIdx.x - NE;
        const void* sampsrc = (blk < 32) ? W1 : (blk < 64 ? W2 : Wfc);
        const uint32_t* samp = (const uint32_t*)sampsrc;
        if (t == 0) hits = 0;
        __syncthreads();
        unsigned ew = (samp[t] >> 7) & 0xFFu;
        unsigned long long bl = __ballot(ew >= 0x60u && ew <= 0x90u);
        if ((t & 63) == 0) atomicAdd(&hits, (int)__popcll(bl));
        __syncthreads();
        int isbf = (2 * hits > 256);

        if (blk < 64) {
            const void* W = (blk < 32) ? W1 : W2;
            unsigned short* th = (blk < 32) ? Wth1 : Wth2;
            int base = (blk & 31) * 512;
            #pragma unroll
            for (int j = 0; j < 2; j++) {
                int idx = base + t * 2 + j;
                int nn = idx >> 7, k = idx & 127;
                int si = k * 128 + nn;
                float f = isbf ? bfs(((const unsigned short*)W)[si])
                               : ((const float*)W)[si];
                th[nn * 128 + k] = f2bf(f);
            }
        } else {
            int i = (blk - 64) * 256 + t;
            if (i >= 4384) return;
            const void* src; float* dst; int off;
            if (i < 128)       { src = b1;  dst = b1f;  off = i; }
            else if (i < 256)  { src = b2;  dst = b2f;  off = i - 128; }
            else if (i < 4352) { src = Wfc; dst = Wfcf; off = i - 256; }
            else               { src = bfc; dst = bfcf; off = i - 4352; }
            dst[off] = isbf ? bfs(((const unsigned short*)src)[off])
                            : ((const float*)src)[off];
        }
        return;
    }

    // ---- econv part: decode -> deg atomics + direct bucketed write ----
    __shared__ int lflag;
    __shared__ int cnt[8], gbase[8];
    if (t == 0) lflag = 0;
    if (t < 8) cnt[t] = 0;
    __syncthreads();
    if (ei[1 + 2 * t] != 0) atomicOr(&lflag, 1);   // odd words: 0 => int64
    __syncthreads();
    int is32 = lflag;

    int base = blockIdx.x * ECH;
    int s[8], d[8], p[8], slot[8];
    #pragma unroll
    for (int j = 0; j < 8; j++) {
        int e = base + j * 256 + t;
        int ss = 0, dd = 0;
        if (e < E) {
            ss = is32 ? ei[e]     : ei[2 * e];
            dd = is32 ? ei[E + e] : ei[2 * E + 2 * e];
            if ((unsigned)ss >= (unsigned)n) ss = 0;
            if ((unsigned)dd >= (unsigned)n) dd = 0;
            atomicAdd(&deg[dd], 1);            // r8: direct degree count
            int pp = dd / psz;
            if (pp > 7) pp = 7;
            p[j] = pp;
            slot[j] = atomicAdd(&cnt[pp], 1);
        } else p[j] = -1;
        s[j] = ss; d[j] = dd;
    }
    __syncthreads();
    if (t < 8) gbase[t] = atomicAdd(&bcnt[t], cnt[t]);
    __syncthreads();
    #pragma unroll
    for (int j = 0; j < 8; j++) {
        if (p[j] >= 0) {
            int off = gbase[p[j]] + slot[j];
            if (off < CAP) {
                dstb[p[j] * CAP + off] = d[j];
                srcb[p[j] * CAP + off] = s[j];
            }
        }
    }
}

// ---- block sums (+ fused dinv) ------------------------------------------
__global__ void k_bsum(const int* __restrict__ deg, int* __restrict__ bsum,
                       float* __restrict__ dinv, int n) {
    __shared__ int ws[4];
    int t = threadIdx.x, lane = t & 63, w = t >> 6;
    int idx = blockIdx.x * 256 + t;
    int v = (idx < n) ? deg[idx] : 0;
    if (idx < n) dinv[idx] = rsqrtf((float)(v + 1));  // +1 self-loop
    int r = v;
    #pragma unroll
    for (int off = 32; off > 0; off >>= 1) r += __shfl_down(r, off, 64);
    if (lane == 0) ws[w] = r;
    __syncthreads();
    if (t == 0) bsum[blockIdx.x] = ws[0] + ws[1] + ws[2] + ws[3];
}

// ---- apply with self-computed block offset ------------------------------
__launch_bounds__(256)
__global__ void k_bapply2(const int* __restrict__ deg, const int* __restrict__ bsum,
                          int* __restrict__ row_ptr, int* __restrict__ cursor,
                          int n, int nb) {
    __shared__ int wred[4];
    __shared__ int wsum[4];
    __shared__ int boffs;
    int b = blockIdx.x, t = threadIdx.x, lane = t & 63, w = t >> 6;

    int pv = (t < b && t < nb) ? bsum[t] : 0;
    #pragma unroll
    for (int off = 32; off > 0; off >>= 1) pv += __shfl_down(pv, off, 64);
    if (lane == 0) wred[w] = pv;
    __syncthreads();
    if (t == 0) boffs = wred[0] + wred[1] + wred[2] + wred[3];
    __syncthreads();

    int idx = b * 256 + t;
    int v = (idx < n) ? deg[idx] : 0;
    int s = v;
    #pragma unroll
    for (int off = 1; off < 64; off <<= 1) {
        int x = __shfl_up(s, off, 64);
        if (lane >= off) s += x;
    }
    if (lane == 63) wsum[w] = s;
    __syncthreads();
    if (t == 0) {
        int acc = 0;
        #pragma unroll
        for (int i = 0; i < 4; i++) { int x = wsum[i]; wsum[i] = acc; acc += x; }
    }
    __syncthreads();
    int ex = boffs + s - v + wsum[w];
    if (idx < n) {
        row_ptr[idx] = ex;
        cursor[idx]  = ex;
    }
    if (idx == n - 1) row_ptr[n] = ex + v;
}

// ---- GEMM tile body: hs8 = fp8(dinv[row]*(X @ W)) -----------------------
__device__ __forceinline__ void gemm_body(const void* __restrict__ X,
                                          const unsigned short* __restrict__ Wth,
                                          const float* __restrict__ dinv,
                                          uint32_t* __restrict__ hs8,
                                          int n, int tile, int l,
                                          unsigned char* __restrict__ ldsrow) {
    int quad = l >> 4;
    int m16 = l & 15;
    int r0 = tile * 16;

    unsigned ew = (((const uint32_t*)X)[l] >> 7) & 0xFFu;
    unsigned long long bl = __ballot(ew >= 0x60u && ew <= 0x90u);
    int isbf = ((int)__popcll(bl) * 2 > 64) ? 1 : 0;

    int ra = r0 + m16;
    if (ra > n - 1) ra = n - 1;
    bf16x8 ah[4];
    if (isbf) {
        const int4* Xv = (const int4*)X;
        #pragma unroll
        for (int kt = 0; kt < 4; kt++)
            ah[kt] = __builtin_bit_cast(bf16x8, Xv[ra * 16 + kt * 4 + quad]);
    } else {
        const float4* Xf = (const float4*)X;
        #pragma unroll
        for (int kt = 0; kt < 4; kt++) {
            int jj = kt * 4 + quad;
            float4 fa = Xf[ra * 32 + jj * 2];
            float4 fb = Xf[ra * 32 + jj * 2 + 1];
            float v[8] = {fa.x, fa.y, fa.z, fa.w, fb.x, fb.y, fb.z, fb.w};
            bf16x8 h;
            #pragma unroll
            for (int j = 0; j < 8; j++) h[j] = (short)f2bf(v[j]);
            ah[kt] = h;
        }
    }

    float dv[4];
    #pragma unroll
    for (int reg = 0; reg < 4; reg++) {
        int row = r0 + quad * 4 + reg;
        if (row > n - 1) row = n - 1;
        dv[reg] = dinv[row];
    }

    const int4* Wvh = (const int4*)Wth;
    #pragma unroll
    for (int nt = 0; nt < 8; nt++) {
        f32x4 acc = {0.f, 0.f, 0.f, 0.f};
        int brow = (nt * 16 + m16) * 16;
        #pragma unroll
        for (int kt = 0; kt < 4; kt++) {
            bf16x8 bh = __builtin_bit_cast(bf16x8, Wvh[brow + kt * 4 + quad]);
            acc = __builtin_amdgcn_mfma_f32_16x16x32_bf16(ah[kt], bh, acc, 0, 0, 0);
        }
        #pragma unroll
        for (int reg = 0; reg < 4; reg++) {
            float v = acc[reg] * dv[reg];
            int pk = __builtin_amdgcn_cvt_pk_fp8_f32(v, v, 0, false);
            ldsrow[(quad * 4 + reg) * 128 + nt * 16 + m16] = (unsigned char)(pk & 0xFF);
        }
    }
    __syncthreads();
    const uint32_t* l32 = (const uint32_t*)ldsrow;
    #pragma unroll
    for (int i = 0; i < 8; i++) {
        int idx = i * 64 + l;
        int row = idx >> 5;
        int grow = r0 + row;
        if (grow < n) hs8[grow * 32 + (idx & 31)] = l32[idx];
    }
}

// ---- fused: scatter [0,SCB) || GEMM layer-1 [SCB,..) --------------------
// Scatter partitioned (r9): b&7 = partition -> stable XCD -> its L2
// absorbs the random 4B col/cursor writes (r8 flat version: 51MB write amp).
__launch_bounds__(256)
__global__ void k_sg(const int* __restrict__ dstb, const int* __restrict__ srcb,
                     const int* __restrict__ bcnt,
                     int* __restrict__ cursor, int* __restrict__ col, int E,
                     const void* __restrict__ X,
                     const unsigned short* __restrict__ Wth,
                     const float* __restrict__ dinv,
                     uint32_t* __restrict__ hs8, int n) {
    __shared__ unsigned char lds8[4][16 * 128];
    int b = blockIdx.x;
    if (b < SCB) {
        int p = b & 7;
        int nb = SCB >> 3;
        int cnt = bcnt[p]; if (cnt > CAP) cnt = CAP;
        const int* db = dstb + p * CAP;
        const int* sb = srcb + p * CAP;
        for (int i = (b >> 3) * 256 + threadIdx.x; i < cnt; i += nb * 256) {
            int pos = atomicAdd(&cursor[db[i]], 1);
            if ((unsigned)pos < (unsigned)E) col[pos] = sb[i];
        }
        return;
    }
    int wave = threadIdx.x >> 6;
    int l = threadIdx.x & 63;
    gemm_body(X, Wth, dinv, hs8, n, (b - SCB) * 4 + wave, l, lds8[wave]);
}

// ---- fused agg-1 + GEMM-2: block owns 16 nodes --------------------------
// Phase A (r4 structure, r7 gather width): 4 waves x 4 sequential nodes.
//   QUAD-ROW int2 gather: lane = edge-slot (lane>>4, 0..3) x int2-quad
//   (lane&15); one VMEM fetches FOUR 128B rows (8B/lane). Masked tail round.
// Phase B: 16-row MFMA tile vs Wth2; each wave 2 nt-slices; fp8 pack+store.
__launch_bounds__(256)
__global__ void k_agg1gemm2(const unsigned short* __restrict__ hsv,
                            const int* __restrict__ row_ptr,
                            const int* __restrict__ col,
                            const float* __restrict__ dinv,
                            const float* __restrict__ bias,
                            const unsigned short* __restrict__ Wth2,
                            uint32_t* __restrict__ hs8out, int n, int E) {
    __shared__ __align__(16) unsigned short actlds[16 * 136]; // stride 136: bank-safe
    __shared__ unsigned char pack[16 * 128];
    int wave = threadIdx.x >> 6;
    int lane = threadIdx.x & 63;
    int q16 = lane & 15;          // int2-quad within row (0..15)
    int slot = lane >> 4;         // edge slot (0..3)
    int tile0 = blockIdx.x * 16;
    const int2* hsw2 = (const int2*)hsv;   // row = 16 int2 (128 fp8)

    // hoisted independent loads: 5 row_ptr + 4 self rows, all in flight
    int base_node = tile0 + wave * 4;
    int rp[5];
    #pragma unroll
    for (int k = 0; k < 5; k++) {
        int nn = base_node + k;
        if (nn > n) nn = n;
        rp[k] = row_ptr[nn];
    }
    int nd4[4]; int2 selfw4[4];
    #pragma unroll
    for (int k = 0; k < 4; k++) {
        int node = base_node + k;
        nd4[k] = (node < n) ? node : 0;
        selfw4[k] = hsw2[nd4[k] * 16 + q16];
    }

    // Phase A: aggregation (hs pre-scaled by dinv[src]; apply dinv[d]+bias+relu)
    #pragma unroll
    for (int i = 0; i < 4; i++) {
        int node = base_node + i;
        bool active = (node < n);
        int nd = nd4[i];

        int e = rp[i];
        int end = active ? rp[i + 1] : e;
        if (e < 0) e = 0;
        if (end > E) end = E;
        if (end < e) end = e;

        float a[8];
        #pragma unroll
        for (int j = 0; j < 8; j++) a[j] = 0.f;
        acc8(selfw4[i], (slot == 0) ? 1.0f : 0.0f, a);   // self counted once

        for (; e + 16 <= end; e += 16) {
            int2 uu[4];
            #pragma unroll
            for (int j = 0; j < 4; j++) {
                unsigned s = (unsigned)col[e + 4 * j + slot];
                if (s >= (unsigned)n) s = 0;
                uu[j] = hsw2[s * 16 + q16];
            }
            #pragma unroll
            for (int j = 0; j < 4; j++) acc8(uu[j], 1.0f, a);
        }
        if (e < end) {                      // ONE masked round covers the tail
            int2 uu[4];
            #pragma unroll
            for (int j = 0; j < 4; j++) {
                int ej = e + 4 * j + slot;
                int ec = (ej < end) ? ej : (end - 1);
                unsigned s = (unsigned)col[ec];
                if (s >= (unsigned)n) s = 0;
                uu[j] = hsw2[s * 16 + q16];
            }
            #pragma unroll
            for (int j = 0; j < 4; j++) {
                float m = ((e + 4 * j + slot) < end) ? 1.0f : 0.0f;
                acc8(uu[j], m, a);
            }
        }
        // combine the 4 edge-slots (xor bits 4,5; q16 = bits 0-3 preserved)
        #pragma unroll
        for (int j = 0; j < 8; j++) {
            a[j] += __shfl_xor(a[j], 16, 64);
            a[j] += __shfl_xor(a[j], 32, 64);
        }

        if (slot == 0) {   // lanes 0..15 hold features [8*q16, 8*q16+8)
            float dv = dinv[nd];
            const float4* b4 = (const float4*)bias;
            float4 b0 = b4[2 * q16];
            float4 b1q = b4[2 * q16 + 1];
            float r0 = fmaxf(dv * a[0] + b0.x, 0.f);
            float r1 = fmaxf(dv * a[1] + b0.y, 0.f);
            float r2 = fmaxf(dv * a[2] + b0.z, 0.f);
            float r3 = fmaxf(dv * a[3] + b0.w, 0.f);
            float r4 = fmaxf(dv * a[4] + b1q.x, 0.f);
            float r5 = fmaxf(dv * a[5] + b1q.y, 0.f);
            float r6 = fmaxf(dv * a[6] + b1q.z, 0.f);
            float r7 = fmaxf(dv * a[7] + b1q.w, 0.f);
            if (!active) { r0=0.f;r1=0.f;r2=0.f;r3=0.f;r4=0.f;r5=0.f;r6=0.f;r7=0.f; }
            int row = wave * 4 + i;
            uint4 w;
            w.x = (uint32_t)f2bf(r0) | ((uint32_t)f2bf(r1) << 16);
            w.y = (uint32_t)f2bf(r2) | ((uint32_t)f2bf(r3) << 16);
            w.z = (uint32_t)f2bf(r4) | ((uint32_t)f2bf(r5) << 16);
            w.w = (uint32_t)f2bf(r6) | ((uint32_t)f2bf(r7) << 16);
            *(uint4*)&actlds[row * 136 + 8 * q16] = w;   // byte 272*row+16*q16
        }
    }
    __syncthreads();

    // Phase B: MFMA tile (A from actlds; 16B-aligned: 136*2=272=16*17)
    int quad = lane >> 4;
    int m16 = lane & 15;
    bf16x8 ah[4];
    #pragma unroll
    for (int kt = 0; kt < 4; kt++) {
        const unsigned short* p = &actlds[m16 * 136 + kt * 32 + quad * 8];
        ah[kt] = __builtin_bit_cast(bf16x8, *(const int4*)p);
    }
    float dv4[4];
    #pragma unroll
    for (int reg = 0; reg < 4; reg++) {
        int row = tile0 + quad * 4 + reg;
        if (row > n - 1) row = n - 1;
        dv4[reg] = dinv[row];
    }
    const int4* Wvh = (const int4*)Wth2;
    #pragma unroll
    for (int ntl = 0; ntl < 2; ntl++) {
        int nt = wave * 2 + ntl;
        f32x4 acc = {0.f, 0.f, 0.f, 0.f};
        int brow = (nt * 16 + m16) * 16;
        #pragma unroll
        for (int kt = 0; kt < 4; kt++) {
            bf16x8 bh = __builtin_bit_cast(bf16x8, Wvh[brow + kt * 4 + quad]);
            acc = __builtin_amdgcn_mfma_f32_16x16x32_bf16(ah[kt], bh, acc, 0, 0, 0);
        }
        #pragma unroll
        for (int reg = 0; reg < 4; reg++) {
            float v = acc[reg] * dv4[reg];
            int pk = __builtin_amdgcn_cvt_pk_fp8_f32(v, v, 0, false);
            pack[(quad * 4 + reg) * 128 + nt * 16 + m16] = (unsigned char)(pk & 0xFF);
        }
    }
    __syncthreads();
    const uint32_t* l32 = (const uint32_t*)pack;
    #pragma unroll
    for (int i = 0; i < 2; i++) {
        int idx = i * 256 + threadIdx.x;   // 0..511
        int row = idx >> 5;
        int grow = tile0 + row;
        if (grow < n) hs8out[grow * 32 + (idx & 31)] = l32[idx];
    }
}

// ---- Pull aggregation layer-2 (fp8 hs, pre-scaled) -> pooled partials ---
// Quad-row int2 gather + single masked tail round (same as agg1gemm2).
__launch_bounds__(256)
__global__ void k_agg(const unsigned short* __restrict__ hsv,
                      const int* __restrict__ row_ptr,
                      const int* __restrict__ col, const float* __restrict__ dinv,
                      const float* __restrict__ bias,
                      float* __restrict__ partial, int n, int E) {
    __shared__ __align__(16) float pl[4][128];
    int wave = threadIdx.x >> 6;
    int lane = threadIdx.x & 63;
    int q16 = lane & 15;
    int slot = lane >> 4;
    int node = blockIdx.x * 4 + wave;
    bool active = (node < n);
    int nd = active ? node : 0;
    const int2* hsw2 = (const int2*)hsv;

    int2 selfw = hsw2[nd * 16 + q16];
    int e = row_ptr[nd];
    int end = active ? row_ptr[nd + 1] : e;
    if (e < 0) e = 0;
    if (end > E) end = E;
    if (end < e) end = e;

    float a[8];
    #pragma unroll
    for (int j = 0; j < 8; j++) a[j] = 0.f;
    acc8(selfw, (slot == 0) ? 1.0f : 0.0f, a);

    for (; e + 16 <= end; e += 16) {
        int2 uu[4];
        #pragma unroll
        for (int j = 0; j < 4; j++) {
            unsigned s = (unsigned)col[e + 4 * j + slot];
            if (s >= (unsigned)n) s = 0;
            uu[j] = hsw2[s * 16 + q16];
        }
        #pragma unroll
        for (int j = 0; j < 4; j++) acc8(uu[j], 1.0f, a);
    }
    if (e < end) {                          // ONE masked round covers the tail
        int2 uu[4];
        #pragma unroll
        for (int j = 0; j < 4; j++) {
            int ej = e + 4 * j + slot;
            int ec = (ej < end) ? ej : (end - 1);
            unsigned s = (unsigned)col[ec];
            if (s >= (unsigned)n) s = 0;
            uu[j] = hsw2[s * 16 + q16];
        }
        #pragma unroll
        for (int j = 0; j < 4; j++) {
            float m = ((e + 4 * j + slot) < end) ? 1.0f : 0.0f;
            acc8(uu[j], m, a);
        }
    }
    #pragma unroll
    for (int j = 0; j < 8; j++) {
        a[j] += __shfl_xor(a[j], 16, 64);
        a[j] += __shfl_xor(a[j], 32, 64);
    }

    if (slot == 0) {       // lanes 0..15: features [8*q16, 8*q16+8)
        float dv = dinv[nd];
        const float4* b4 = (const float4*)bias;
        float4 b0 = b4[2 * q16];
        float4 b1q = b4[2 * q16 + 1];
        float4 ra, rb;
        ra.x = fmaxf(dv * a[0] + b0.x, 0.f);
        ra.y = fmaxf(dv * a[1] + b0.y, 0.f);
        ra.z = fmaxf(dv * a[2] + b0.z, 0.f);
        ra.w = fmaxf(dv * a[3] + b0.w, 0.f);
        rb.x = fmaxf(dv * a[4] + b1q.x, 0.f);
        rb.y = fmaxf(dv * a[5] + b1q.y, 0.f);
        rb.z = fmaxf(dv * a[6] + b1q.z, 0.f);
        rb.w = fmaxf(dv * a[7] + b1q.w, 0.f);
        if (!active) {
            ra.x=0.f;ra.y=0.f;ra.z=0.f;ra.w=0.f;
            rb.x=0.f;rb.y=0.f;rb.z=0.f;rb.w=0.f;
        }
        *(float4*)&pl[wave][8 * q16]     = ra;   // byte 32*q16 (16B aligned)
        *(float4*)&pl[wave][8 * q16 + 4] = rb;
    }
    __syncthreads();
    int t = threadIdx.x;
    if (t < 128) {
        float ps = pl[0][t] + pl[1][t] + pl[2][t] + pl[3][t];
        partial[blockIdx.x * 128 + t] = ps;
    }
}

// ---- fused pooled reduce + FC (last-block pattern) ----------------------
__launch_bounds__(256)
__global__ void k_redfinal(const float* __restrict__ partial, float* __restrict__ pooled,
                           int* __restrict__ done,
                           const float* __restrict__ Wfcf, const float* __restrict__ bfcf,
                           const void* __restrict__ x, void* __restrict__ out,
                           int n, int nbrows, int gblocks) {
    __shared__ float red[8][128];
    int t = threadIdx.x;
    int chunk = (nbrows + gblocks - 1) / gblocks;
    int r0 = blockIdx.x * chunk;
    int r1 = r0 + chunk;
    if (r1 > nbrows) r1 = nbrows;

    float4 acc = {0.f, 0.f, 0.f, 0.f};
    const float4* p4 = (const float4*)partial;
    for (int i = r0 * 32 + t; i < r1 * 32; i += 256) {
        float4 v = p4[i];
        acc.x += v.x; acc.y += v.y; acc.z += v.z; acc.w += v.w;
    }
    int g = t >> 5;
    int fb = (t & 31) * 4;
    red[g][fb]     = acc.x;
    red[g][fb + 1] = acc.y;
    red[g][fb + 2] = acc.z;
    red[g][fb + 3] = acc.w;
    __syncthreads();
    if (t < 128) {
        float s = red[0][t] + red[1][t] + red[2][t] + red[3][t]
                + red[4][t] + red[5][t] + red[6][t] + red[7][t];
        atomicAdd(&pooled[t], s);
    }
    __threadfence();
    __shared__ int lastf;
    if (t == 0) lastf = (atomicAdd(done, 1) == gblocks - 1) ? 1 : 0;
    __syncthreads();
    if (!lastf) return;

    __shared__ int hits;
    __shared__ float pv[128];
    if (t == 0) hits = 0;
    __syncthreads();
    unsigned ew = (((const uint32_t*)x)[t] >> 7) & 0xFFu;
    unsigned long long bl = __ballot(ew >= 0x60u && ew <= 0x90u);
    if ((t & 63) == 0) atomicAdd(&hits, (int)__popcll(bl));
    if (t < 128)
        pv[t] = __hip_atomic_load(&pooled[t], __ATOMIC_RELAXED,
                                  __HIP_MEMORY_SCOPE_AGENT);
    __syncthreads();
    int isbf = (2 * hits > 256);
    if (t < 32) {
        float s = 0.f;
        for (int c = 0; c < 128; ++c) s += pv[c] * Wfcf[c * 32 + t];
        s = s * (1.0f / (float)n) + bfcf[t];
        if (isbf) ((unsigned short*)out)[t] = f2bf(s);
        else      ((float*)out)[t] = s;
    }
}

// ---- Launch -------------------------------------------------------------

extern "C" void kernel_launch(void* const* d_in, const int* in_sizes, int n_in,
                              void* d_out, int out_size, void* d_ws, size_t ws_size,
                              hipStream_t stream) {
    const void* x   = d_in[0];
    const int*  ei  = (const int*)d_in[1];
    const void* W1  = d_in[2];
    const void* b1  = d_in[3];
    const void* W2  = d_in[4];
    const void* b2  = d_in[5];
    const void* Wfc = d_in[6];
    const void* bfc = d_in[7];

    const int n = in_sizes[0] / FEAT;    // 50000
    const int E = in_sizes[1] / 2;       // 800000
    const int nagg = (n + 3) / 4;        // 12500
    const int ntile = (n + 15) / 16;     // 3125
    const int psz  = (n + 7) / 8;        // 6250
    const int nscan = (n + 255) / 256;   // 196
    const int NE   = (E + ECH - 1) / ECH;// 391
    const int gemm_grid = (ntile + 3) / 4; // 782

    char* ws = (char*)d_ws;
    uint32_t*       hs8     = (uint32_t*)(ws);                     // 6.4MB used
    uint32_t*       hs8b    = (uint32_t*)(ws + 12800000);          // 6.4MB (layer-2 hs)
    float*          partial = (float*)(ws + 25600000);             // 6.4MB used
    int*            col     = (int*)(ws + 38400000);               // 3.2MB
    int*            dstb    = (int*)(ws + 41600000);               // 6.4MB (8*CAP)
    int*            srcb    = (int*)(ws + 48000000);               // 6.4MB
    // merged zero region (ONE memset): deg | pooled | bcnt | done | bsum
    int*            deg     = (int*)(ws + 54400000);               // 200,000
    float*          pooled  = (float*)(ws + 54600000);             // 512
    int*            bcnt    = (int*)(ws + 54600512);               // 32
    int*            done    = (int*)(ws + 54600544);               // 16
    int*            bsum    = (int*)(ws + 54600560);               // 784 -> end 54601344
    int*            row_ptr = (int*)(ws + 54601344);               // 200,016
    int*            cursor  = (int*)(ws + 54801360);               // 200,000
    float*          dinv    = (float*)(ws + 55001360);             // 200,000
    unsigned short* Wth1    = (unsigned short*)(ws + 55201360);    // 32,768
    unsigned short* Wth2    = (unsigned short*)(ws + 55234128);    // 32,768
    float*          b1f     = (float*)(ws + 55266896);             // 512
    float*          b2f     = (float*)(ws + 55267408);             // 512
    float*          Wfcf    = (float*)(ws + 55267920);             // 16,384
    float*          bfcf    = (float*)(ws + 55284304);             // 128 -> end 55284432

    if (ws_size < 55284448) return;  // diagnostic: zero output => ws too small

    hipMemsetAsync(deg, 0, 201344, stream);   // r11: single merged memset

    // 1) fused prep: decode + deg atomics + direct partition bucketing | W prep
    k_prep<<<NE + 82, 256, 0, stream>>>(ei, dstb, srcb, bcnt, deg, E, n, psz, NE,
                                        W1, W2, b1, b2, Wfc, bfc,
                                        Wth1, Wth2, b1f, b2f, Wfcf, bfcf);
    // 2) CSR scan
    k_bsum<<<nscan, 256, 0, stream>>>(deg, bsum, dinv, n);
    k_bapply2<<<nscan, 256, 0, stream>>>(deg, bsum, row_ptr, cursor, n, nscan);
    // 3) fused: partitioned scatter || GEMM layer-1
    k_sg<<<SCB + gemm_grid, 256, 0, stream>>>(dstb, srcb, bcnt, cursor, col, E,
                                              x, Wth1, dinv, hs8, n);
    // 4) fused agg-1 + GEMM-2 (r7 quad-row gather, unchanged)
    k_agg1gemm2<<<ntile, 256, 0, stream>>>((const unsigned short*)hs8, row_ptr,
                                           col, dinv, b1f, Wth2, hs8b, n, E);
    // 5) agg-2 -> pooled partials (unchanged)
    k_agg<<<nagg, 256, 0, stream>>>((const unsigned short*)hs8b, row_ptr, col,
                                    dinv, b2f, partial, n, E);
    // 6) fused pooled-reduce + FC
    k_redfinal<<<100, 256, 0, stream>>>(partial, pooled, done, Wfcf, bfcf,
                                        x, d_out, n, nagg, 100);
}